// Round 5
// baseline (478.318 us; speedup 1.0000x reference)
//
#include <hip/hip_runtime.h>

typedef unsigned short ushort_t;
typedef float  f32x4   __attribute__((ext_vector_type(4)));
typedef float  f32x16  __attribute__((ext_vector_type(16)));
typedef __bf16 bf16x4  __attribute__((ext_vector_type(4)));
typedef __bf16 bf16x8  __attribute__((ext_vector_type(8)));
typedef unsigned uint2v __attribute__((ext_vector_type(2)));

#define MFMA16(a,b,c) __builtin_amdgcn_mfma_f32_16x16x32_bf16((a),(b),(c),0,0,0)
#define MFMA32(a,b,c) __builtin_amdgcn_mfma_f32_32x32x16_bf16((a),(b),(c),0,0,0)

__device__ __forceinline__ ushort_t f2bf(float f) {
  union { float f; unsigned u; } v; v.f = f;
  unsigned u = v.u;
  unsigned r = u + 0x7FFFu + ((u >> 16) & 1u);   // round-to-nearest-even
  return (ushort_t)(r >> 16);
}
__device__ __forceinline__ float bf2f(ushort_t s) {
  union { unsigned u; float f; } v; v.u = ((unsigned)s) << 16;
  return v.f;
}

// swap lanes 32-63 of a with lanes 0-31 of b (v_permlane32_swap_b32)
__device__ __forceinline__ void plswap(unsigned& a, unsigned& b) {
#if __has_builtin(__builtin_amdgcn_permlane32_swap)
  uint2v r = __builtin_amdgcn_permlane32_swap(a, b, false, false);
  a = r[0]; b = r[1];
#else
  asm("v_permlane32_swap_b32 %0, %1" : "+v"(a), "+v"(b));
#endif
}

// async global->LDS, 16B per lane. LDS dest is wave-uniform-base + lane*16;
// global src is per-lane (this is how the source-side swizzle is applied).
__device__ __forceinline__ void gload_lds16(const ushort_t* g, ushort_t* l) {
  __builtin_amdgcn_global_load_lds(
      (const __attribute__((address_space(1))) unsigned int*)g,
      (__attribute__((address_space(3))) unsigned int*)l, 16, 0, 0);
}

// ---------------------------------------------------------------------------
// Kernel 1: fused grouped conv (MFMA) + bias; x staged once per block (f32 ->
// bf16 transpose in LDS), loops 3 branches x 4 ngsub. Writes unnormalized y
// in final layouts; accumulates GroupNorm partial sums via atomics.
// grid (pc=16, g*b=64), 256 thr.
// Q branch -> [B][C][P]; K/V branches -> [B][H][P][128].
// ---------------------------------------------------------------------------
__global__ __launch_bounds__(256) void conv_gn(
    const float* __restrict__ x,
    const float* __restrict__ wq, const float* __restrict__ wk, const float* __restrict__ wv,
    const float* __restrict__ bq, const float* __restrict__ bk, const float* __restrict__ bv,
    ushort_t* __restrict__ Qb, ushort_t* __restrict__ Kb, ushort_t* __restrict__ Vb,
    float* __restrict__ stats) {
  int pc = blockIdx.x;
  int gz = blockIdx.y;
  int b = gz & 7, g = gz >> 3;
  int tid = threadIdx.x, lane = tid & 63, wid = tid >> 6;
  int l15 = lane & 15, q = lane >> 4;

  __shared__ __align__(16) ushort_t xl[128 * 72];   // [p][f]
  __shared__ __align__(16) ushort_t wl[128 * 72];   // [co][f], one branch
  __shared__ __align__(16) ushort_t yl[128 * 40];   // staging (br=0 uses [32][136])
  __shared__ float biasl[128];
  __shared__ float redbuf[8];

  // stage x tile [64 f][128 p] f32 -> xl[p][f] bf16
  const float* xsrc = x + ((size_t)(b * 512 + g * 64)) * 2048 + pc * 128;
#pragma unroll
  for (int r = 0; r < 8; ++r) {
    int chunk = tid + 256 * r;
    int c = chunk >> 5, p4 = chunk & 31;
    float4 v = *(const float4*)&xsrc[(size_t)c * 2048 + p4 * 4];
    xl[(p4 * 4 + 0) * 72 + c] = f2bf(v.x);
    xl[(p4 * 4 + 1) * 72 + c] = f2bf(v.y);
    xl[(p4 * 4 + 2) * 72 + c] = f2bf(v.z);
    xl[(p4 * 4 + 3) * 72 + c] = f2bf(v.w);
  }
  __syncthreads();

  // resident B-frags (wave's 32 p-cols)
  bf16x8 Bx[2][2];
#pragma unroll
  for (int n2 = 0; n2 < 2; ++n2)
#pragma unroll
    for (int kk = 0; kk < 2; ++kk)
      Bx[n2][kk] = *(const bf16x8*)&xl[((wid * 2 + n2) * 16 + l15) * 72 + kk * 32 + q * 8];

  for (int br = 0; br < 3; ++br) {
    const float* w    = (br == 0) ? wq : ((br == 1) ? wk : wv);
    const float* bias = (br == 0) ? bq : ((br == 1) ? bk : bv);
    ushort_t* dst     = (br == 0) ? Qb : ((br == 1) ? Kb : Vb);
    __syncthreads();   // previous branch's wl/yl consumers done
    const float* wsrc = w + (size_t)g * 128 * 64;
#pragma unroll
    for (int r = 0; r < 8; ++r) {
      int idx = (tid + 256 * r) << 2;
      float4 v = *(const float4*)&wsrc[idx];
      int row = idx >> 6, f = idx & 63;
      bf16x4 wv4 = {(__bf16)v.x, (__bf16)v.y, (__bf16)v.z, (__bf16)v.w};
      *(bf16x4*)&wl[row * 72 + f] = wv4;
    }
    if (tid < 128) biasl[tid] = bias[g * 128 + tid];
    __syncthreads();

    for (int ngs = 0; ngs < 4; ++ngs) {
      int co0 = ngs * 32;
      bf16x8 Aw[2][2];
#pragma unroll
      for (int m = 0; m < 2; ++m)
#pragma unroll
        for (int kk = 0; kk < 2; ++kk)
          Aw[m][kk] = *(const bf16x8*)&wl[(co0 + m * 16 + l15) * 72 + kk * 32 + q * 8];
      // acc[a][b]: br==0 (swapped): a = n2 (p-tile), b = mw (co-tile);
      //            br>=1:           a = m  (co),     b = n2 (p)
      f32x4 acc[2][2];
#pragma unroll
      for (int a = 0; a < 2; ++a)
#pragma unroll
        for (int c2 = 0; c2 < 2; ++c2) acc[a][c2] = (f32x4){0.f, 0.f, 0.f, 0.f};
      if (br == 0) {
#pragma unroll
        for (int kk = 0; kk < 2; ++kk)
#pragma unroll
          for (int n2 = 0; n2 < 2; ++n2)
#pragma unroll
            for (int mw = 0; mw < 2; ++mw)
              acc[n2][mw] = MFMA16(Bx[n2][kk], Aw[mw][kk], acc[n2][mw]);
      } else {
#pragma unroll
        for (int kk = 0; kk < 2; ++kk)
#pragma unroll
          for (int n2 = 0; n2 < 2; ++n2)
#pragma unroll
            for (int m = 0; m < 2; ++m)
              acc[m][n2] = MFMA16(Aw[m][kk], Bx[n2][kk], acc[m][n2]);
      }

      float s1 = 0.f, s2 = 0.f;
      if (br == 0) {   // c = co0 + mw*16 + l15 (one bias per frag)
#pragma unroll
        for (int n2 = 0; n2 < 2; ++n2)
#pragma unroll
          for (int mw = 0; mw < 2; ++mw) {
            float bi = biasl[co0 + mw * 16 + l15];
#pragma unroll
            for (int rg = 0; rg < 4; ++rg) {
              float y = acc[n2][mw][rg] + bi;
              acc[n2][mw][rg] = y;
              s1 += y; s2 += y * y;
            }
          }
      } else {         // c = co0 + m*16 + 4q + rg
#pragma unroll
        for (int m = 0; m < 2; ++m)
#pragma unroll
          for (int n2 = 0; n2 < 2; ++n2)
#pragma unroll
            for (int rg = 0; rg < 4; ++rg) {
              float y = acc[m][n2][rg] + biasl[co0 + m * 16 + 4 * q + rg];
              acc[m][n2][rg] = y;
              s1 += y; s2 += y * y;
            }
      }
#pragma unroll
      for (int mask = 32; mask >= 1; mask >>= 1) {
        s1 += __shfl_xor(s1, mask, 64);
        s2 += __shfl_xor(s2, mask, 64);
      }

      __syncthreads();   // previous ngs's yl global-store reads done
      if (lane == 0) { redbuf[wid * 2] = s1; redbuf[wid * 2 + 1] = s2; }
      if (br == 0) {   // yl: [32 c][136 p]; row = co_local (l15), cols = p (regs)
#pragma unroll
        for (int n2 = 0; n2 < 2; ++n2)
#pragma unroll
          for (int mw = 0; mw < 2; ++mw) {
            bf16x4 pk = {(__bf16)acc[n2][mw][0], (__bf16)acc[n2][mw][1],
                         (__bf16)acc[n2][mw][2], (__bf16)acc[n2][mw][3]};
            *(bf16x4*)&yl[(mw * 16 + l15) * 136 + (wid * 2 + n2) * 16 + 4 * q] = pk;
          }
      } else {         // yl: [128 p][40 c]; row = p (l15), cols = c (regs)
#pragma unroll
        for (int m = 0; m < 2; ++m)
#pragma unroll
          for (int n2 = 0; n2 < 2; ++n2) {
            bf16x4 pk = {(__bf16)acc[m][n2][0], (__bf16)acc[m][n2][1],
                         (__bf16)acc[m][n2][2], (__bf16)acc[m][n2][3]};
            *(bf16x4*)&yl[((wid * 2 + n2) * 16 + l15) * 40 + m * 16 + 4 * q] = pk;
          }
      }
      __syncthreads();

      if (br == 0) {
#pragma unroll
        for (int r = 0; r < 2; ++r) {
          int chunk = tid + 256 * r;
          int row = chunk >> 4, ch = chunk & 15;
          *(uint4*)&dst[((size_t)(b * 1024 + g * 128 + co0 + row)) * 2048 + pc * 128 + ch * 8] =
              *(const uint4*)&yl[row * 136 + ch * 8];
        }
      } else {
#pragma unroll
        for (int r = 0; r < 2; ++r) {
          int chunk = tid + 256 * r;
          int row = chunk >> 2, ch = chunk & 3;
          *(uint4*)&dst[((size_t)(b * 8 + g) * 2048 + pc * 128 + row) * 128 + co0 + ch * 8] =
              *(const uint4*)&yl[row * 40 + ch * 8];
        }
      }
      if (tid == 0) {
        float S1 = redbuf[0] + redbuf[2] + redbuf[4] + redbuf[6];
        float S2 = redbuf[1] + redbuf[3] + redbuf[5] + redbuf[7];
        int sidx = (br * 8 + b) * 32 + g * 4 + ngs;
        atomicAdd(&stats[2 * sidx], S1);
        atomicAdd(&stats[2 * sidx + 1], S2);
      }
    }
  }
}

// ---------------------------------------------------------------------------
// Kernel 2: in-place GroupNorm affine + LeakyReLU over the 3 contiguous bufs.
// grid-stride (2048 blocks x 12 iters).
// ---------------------------------------------------------------------------
__global__ __launch_bounds__(256) void gn_apply(
    ushort_t* __restrict__ buf, const float* __restrict__ stats,
    const float* __restrict__ gw1, const float* __restrict__ gb1,
    const float* __restrict__ gw2, const float* __restrict__ gb2,
    const float* __restrict__ gw3, const float* __restrict__ gb3) {
  const unsigned NQ = 16777216u;
  unsigned base = blockIdx.x * 256 + threadIdx.x;   // 524288 threads
  for (int itn = 0; itn < 12; ++itn) {
    unsigned gid = base + (unsigned)itn * 524288u;
    unsigned e = gid * 8;
    int br; unsigned local;
    if (e < NQ)            { br = 0; local = e; }
    else if (e < 2u * NQ)  { br = 1; local = e - NQ; }
    else                   { br = 2; local = e - 2u * NQ; }
    int b, c0;
    if (br == 0) { b = local >> 21; c0 = (local >> 11) & 1023; }
    else {
      int cih = local & 127; int h = (local >> 18) & 7;
      b = local >> 21; c0 = h * 128 + cih;
    }
    int ng = c0 >> 5;
    const float* gw = (br == 0) ? gw1 : ((br == 1) ? gw2 : gw3);
    const float* gb = (br == 0) ? gb1 : ((br == 1) ? gb2 : gb3);
    int sidx = (br * 8 + b) * 32 + ng;
    float mean = stats[2 * sidx] * (1.f / 65536.f);
    float var  = stats[2 * sidx + 1] * (1.f / 65536.f) - mean * mean;
    float rstd = rsqrtf(var + 1e-5f);
    uint4 d = *(uint4*)&buf[(size_t)e];
    ushort_t* pu = (ushort_t*)&d;
#pragma unroll
    for (int i = 0; i < 8; ++i) {
      int ci = (br == 0) ? c0 : (c0 + i);
      float a = rstd * gw[ci];
      float b2 = gb[ci] - mean * a;
      float yn = fmaf(bf2f(pu[i]), a, b2);
      yn = (yn >= 0.f) ? yn : 0.1f * yn;
      pu[i] = f2bf(yn);
    }
    *(uint4*)&buf[(size_t)e] = d;
  }
}

// ---------------------------------------------------------------------------
// Kernel 3: flash attention, 32x32x16 MFMA, S^T formulation.
// flashQ=K-branch [B,H,P,128] (i), flashK=V-branch [B,H,P,128] (j),
// flashV=Q-branch [B,C,P] (c rows, p=j cols).
// Block: i-tile 256 (4 waves x 64 i = 2 n-tiles), grid (8,64) + XCD remap.
//
// R10 vs R9 (174us): register file is at the 256/wave cap (128 VGPR + 128
// AGPR) -> occupancy fixed at 2 blocks/CU; HBM 8.8%; the unexplained ~3k
// cy/jt is per-iteration sync: 64 barriers whose implicit vmcnt(0) drain
// has a hiding window (1 jt ~600cy) SHORTER than first-touch HBM latency
// (~900cy).
//  * j-loop unrolled x2: stage 64 j-rows per buffer; ONE barrier + ONE
//    drain per TWO j-tiles; prefetch hiding window doubles to ~1200cy >
//    HBM latency; barrier/convergence events halve. Sub-tiles processed
//    sequentially (ST/Bp regs reused -> no register growth). LDS 64KB,
//    still exactly 2 blocks/CU.
//  * vmax reduce as max3-friendly tree (15 -> 8 ops).
//  * kept: T12 register-P (cvt_pk + permlane32_swap), XCD remap (lin%8 ->
//    bh&7), T5 setprio, defer-max, exp2 softmax, source-side XOR swizzles,
//    launch_bounds(256,2) (DO NOT lower: (256,4) => 64 VGPR => 24MB spill).
// ---------------------------------------------------------------------------
__global__ __launch_bounds__(256, 2) void attn(
    const ushort_t* __restrict__ Qb, const ushort_t* __restrict__ Kb,
    const ushort_t* __restrict__ Vb, float* __restrict__ out) {
  __shared__ __align__(16) ushort_t fKs[2][64 * 128];   // [j][d] linear, 2x16KB
  __shared__ __align__(16) ushort_t Vs[2][128 * 64];    // [c][j] linear, 2x16KB

  int lin = blockIdx.x + 8 * blockIdx.y;           // XCD = lin % 8
  int it = (lin >> 3) & 7;
  int bh = (lin & 7) + 8 * (lin >> 6);             // XCD = bh & 7
  int b = bh >> 3, h = bh & 7;
  int tid = threadIdx.x, lane = tid & 63, wid = tid >> 6;
  int l31 = lane & 31, q2 = lane >> 5;
  // scale*log2(e): softmax in exp2 domain
  const float sl = 0.08838834764831845f * 1.4426950408889634f;

  // resident fQ B-frags: B[k=d][n=i], n-col = l31 -> row i (one-time load)
  bf16x8 Bq[2][8];
#pragma unroll
  for (int nt = 0; nt < 2; ++nt) {
    const ushort_t* fQp =
        Kb + ((size_t)bh * 2048 + it * 256 + wid * 64 + nt * 32 + l31) * 128 + q2 * 8;
#pragma unroll
    for (int dc = 0; dc < 8; ++dc) Bq[nt][dc] = *(const bf16x8*)&fQp[dc * 16];
  }

  float m2[2], l_i[2];
  m2[0] = m2[1] = -3e38f;
  l_i[0] = l_i[1] = 0.f;
  f32x16 O[4][2];
#pragma unroll
  for (int mt = 0; mt < 4; ++mt)
#pragma unroll
    for (int nt = 0; nt < 2; ++nt) O[mt][nt] = (f32x16)(0.f);

  const ushort_t* fKg = Vb + (size_t)bh * 2048 * 128;
  const ushort_t* fVg = Qb + ((size_t)(b * 1024 + h * 128)) * 2048;

  // ---- staging: 64 j-rows (2 j-tiles) per buffer = 1024 16B-units per
  // tensor; each thread issues 4+4. LDS linear in unit index n; XOR swizzle
  // applied on the GLOBAL side.
  // fKs: row kr in [0,64), 16 units/row, swz u^(kr&7).
  // Vs:  row vr in [0,128) (c), 8 units/row (64 j), swz u^((vr>>1)&7).
#define STAGE2(U, NB)                                                          \
  do {                                                                         \
    _Pragma("unroll")                                                          \
    for (int r = 0; r < 4; ++r) {                                              \
      int n = tid + 256 * r;                                                   \
      int kr = n >> 4, ku = (n & 15) ^ (kr & 7);                               \
      gload_lds16(fKg + (size_t)((U) * 64 + kr) * 128 + ku * 8,                \
                  &fKs[NB][n * 8]);                                            \
      int vr = n >> 3, vu = (n & 7) ^ ((vr >> 1) & 7);                         \
      gload_lds16(fVg + (size_t)vr * 2048 + (U) * 64 + vu * 8,                 \
                  &Vs[NB][n * 8]);                                             \
    }                                                                          \
  } while (0)

  STAGE2(0, 0);
  __syncthreads();   // vmcnt(0) drain + barrier: tiles {0,1} visible
  int cur = 0;

  for (int u = 0; u < 32; ++u) {
    if (u < 31) STAGE2(u + 1, cur ^ 1);   // async prefetch, 2-jt hiding window

#pragma unroll
    for (int s = 0; s < 2; ++s) {
      // S^T = fK . fQ^T : 8 swizzled A-reads, 16 MFMAs
      f32x16 ST[2];
      ST[0] = (f32x16)(0.f);
      ST[1] = (f32x16)(0.f);
      __builtin_amdgcn_s_setprio(1);
#pragma unroll
      for (int dc = 0; dc < 8; ++dc) {
        int up = (dc * 2 + q2) ^ (l31 & 7);
        bf16x8 Ak = *(const bf16x8*)&fKs[cur][(s * 32 + l31) * 128 + up * 8];
        ST[0] = MFMA32(Ak, Bq[0][dc], ST[0]);
        ST[1] = MFMA32(Ak, Bq[1][dc], ST[1]);
      }
      __builtin_amdgcn_s_setprio(0);

      // online softmax over j; lane covers i (j split across q2).
      // P -> bf16 MFMA B-frags IN REGISTER via cvt_pk + permlane32_swap.
      bf16x8 Bp[2][2];   // [nt][jc]
#pragma unroll
      for (int nt = 0; nt < 2; ++nt) {
        // max3-friendly reduce tree over 16
        float t0 = fmaxf(fmaxf(ST[nt][0], ST[nt][1]), ST[nt][2]);
        float t1 = fmaxf(fmaxf(ST[nt][3], ST[nt][4]), ST[nt][5]);
        float t2 = fmaxf(fmaxf(ST[nt][6], ST[nt][7]), ST[nt][8]);
        float t3 = fmaxf(fmaxf(ST[nt][9], ST[nt][10]), ST[nt][11]);
        float t4 = fmaxf(fmaxf(ST[nt][12], ST[nt][13]), ST[nt][14]);
        float vmax = fmaxf(fmaxf(fmaxf(t0, t1), t2),
                           fmaxf(fmaxf(t3, t4), ST[nt][15]));
        float v2 = vmax * sl;
        v2 = fmaxf(v2, __shfl_xor(v2, 32, 64));
        float al = 1.f;
        bool need = !__all(v2 <= m2[nt] + 8.f);   // defer-max: wave-uniform
        if (need) {
          float mn2 = fmaxf(m2[nt], v2);
          al = __builtin_amdgcn_exp2f(m2[nt] - mn2);
          m2[nt] = mn2;
        }
        float mn = m2[nt];
        float p16[16];
        float rs = 0.f;
#pragma unroll
        for (int rg = 0; rg < 16; ++rg) {
          p16[rg] = __builtin_amdgcn_exp2f(fmaf(ST[nt][rg], sl, -mn));
          rs += p16[rg];
        }
        rs += __shfl_xor(rs, 32, 64);
        l_i[nt] = l_i[nt] * al + rs;
        if (need) {   // O rescale only when running max moved (i on lanes)
#pragma unroll
          for (int mt = 0; mt < 4; ++mt)
#pragma unroll
            for (int rg = 0; rg < 16; ++rg) O[mt][nt][rg] *= al;
        }
#pragma unroll
        for (int jc = 0; jc < 2; ++jc) {
          unsigned pa, pb, pc_, pd;
          asm("v_cvt_pk_bf16_f32 %0, %1, %2"
              : "=v"(pa) : "v"(p16[jc * 8 + 0]), "v"(p16[jc * 8 + 1]));
          asm("v_cvt_pk_bf16_f32 %0, %1, %2"
              : "=v"(pc_) : "v"(p16[jc * 8 + 2]), "v"(p16[jc * 8 + 3]));
          asm("v_cvt_pk_bf16_f32 %0, %1, %2"
              : "=v"(pb) : "v"(p16[jc * 8 + 4]), "v"(p16[jc * 8 + 5]));
          asm("v_cvt_pk_bf16_f32 %0, %1, %2"
              : "=v"(pd) : "v"(p16[jc * 8 + 6]), "v"(p16[jc * 8 + 7]));
          plswap(pa, pb);
          plswap(pc_, pd);
          union { unsigned u[4]; bf16x8 v; } fr;
          fr.u[0] = pa; fr.u[1] = pc_; fr.u[2] = pb; fr.u[3] = pd;
          Bp[nt][jc] = fr.v;
        }
      }

      // O^T += V . P^T : 8 swizzled V-reads, 16 MFMAs (P in registers)
      __builtin_amdgcn_s_setprio(1);
#pragma unroll
      for (int jc = 0; jc < 2; ++jc) {
#pragma unroll
        for (int mt = 0; mt < 4; ++mt) {
          int row = mt * 32 + l31;
          int up = (s * 4 + jc * 2 + q2) ^ ((row >> 1) & 7);
          bf16x8 Av = *(const bf16x8*)&Vs[cur][row * 64 + up * 8];
          O[mt][0] = MFMA32(Av, Bp[0][jc], O[mt][0]);
          O[mt][1] = MFMA32(Av, Bp[1][jc], O[mt][1]);
        }
      }
      __builtin_amdgcn_s_setprio(0);
    }

    __syncthreads();   // single barrier per 2 j-tiles
    cur ^= 1;
  }
#undef STAGE2

  // epilogue: i on lanes -> direct coalesced stores
  float linv[2];
  linv[0] = 1.f / l_i[0];
  linv[1] = 1.f / l_i[1];
#pragma unroll
  for (int mt = 0; mt < 4; ++mt)
#pragma unroll
    for (int nt = 0; nt < 2; ++nt) {
      float* obase = out + ((size_t)(b * 1024 + h * 128 + mt * 32)) * 2048 +
                     it * 256 + wid * 64 + nt * 32 + l31;
#pragma unroll
      for (int rg = 0; rg < 16; ++rg) {
        int c = (rg & 3) + 8 * (rg >> 2) + 4 * q2;
        obase[(size_t)c * 2048] = O[mt][nt][rg] * linv[nt];
      }
    }
}

// ---------------------------------------------------------------------------
extern "C" void kernel_launch(void* const* d_in, const int* in_sizes, int n_in,
                              void* d_out, int out_size, void* d_ws, size_t ws_size,
                              hipStream_t stream) {
  const float* x   = (const float*)d_in[0];
  const float* wq  = (const float*)d_in[1];
  const float* bq  = (const float*)d_in[2];
  const float* gw1 = (const float*)d_in[3];
  const float* gb1 = (const float*)d_in[4];
  const float* wk  = (const float*)d_in[5];
  const float* bk  = (const float*)d_in[6];
  const float* gw2 = (const float*)d_in[7];
  const float* gb2 = (const float*)d_in[8];
  const float* wv  = (const float*)d_in[9];
  const float* bv  = (const float*)d_in[10];
  const float* gw3 = (const float*)d_in[11];
  const float* gb3 = (const float*)d_in[12];
  float* out = (float*)d_out;
  char* ws = (char*)d_ws;

  ushort_t* Qb = (ushort_t*)(ws);               // 33,554,432 B  [B,C,P] bf16
  ushort_t* Kb = (ushort_t*)(ws + 33554432);    // 33,554,432 B  [B,H,P,128] bf16
  ushort_t* Vb = (ushort_t*)(ws + 67108864);    // 33,554,432 B  [B,H,P,128] bf16
  float* stats = (float*)(ws + 100663296);      // 768 groups x {s1,s2}

  hipMemsetAsync(stats, 0, 1536 * sizeof(float), stream);
  conv_gn<<<dim3(16, 64), 256, 0, stream>>>(x, wq, wk, wv, bq, bk, bv,
                                            Qb, Kb, Vb, stats);
  gn_apply<<<2048, 256, 0, stream>>>(Qb, stats, gw1, gb1, gw2, gb2, gw3, gb3);
  attn<<<dim3(8, 64), 256, 0, stream>>>(Qb, Kb, Vb, out);
}

// Round 6
// 438.818 us; speedup vs baseline: 1.0900x; 1.0900x over previous
//
#include <hip/hip_runtime.h>

typedef unsigned short ushort_t;
typedef float  f32x4   __attribute__((ext_vector_type(4)));
typedef float  f32x16  __attribute__((ext_vector_type(16)));
typedef __bf16 bf16x4  __attribute__((ext_vector_type(4)));
typedef __bf16 bf16x8  __attribute__((ext_vector_type(8)));
typedef unsigned uint2v __attribute__((ext_vector_type(2)));

#define MFMA16(a,b,c) __builtin_amdgcn_mfma_f32_16x16x32_bf16((a),(b),(c),0,0,0)
#define MFMA32(a,b,c) __builtin_amdgcn_mfma_f32_32x32x16_bf16((a),(b),(c),0,0,0)

__device__ __forceinline__ ushort_t f2bf(float f) {
  union { float f; unsigned u; } v; v.f = f;
  unsigned u = v.u;
  unsigned r = u + 0x7FFFu + ((u >> 16) & 1u);   // round-to-nearest-even
  return (ushort_t)(r >> 16);
}
__device__ __forceinline__ float bf2f(ushort_t s) {
  union { unsigned u; float f; } v; v.u = ((unsigned)s) << 16;
  return v.f;
}

// swap lanes 32-63 of a with lanes 0-31 of b (v_permlane32_swap_b32)
__device__ __forceinline__ void plswap(unsigned& a, unsigned& b) {
#if __has_builtin(__builtin_amdgcn_permlane32_swap)
  uint2v r = __builtin_amdgcn_permlane32_swap(a, b, false, false);
  a = r[0]; b = r[1];
#else
  asm("v_permlane32_swap_b32 %0, %1" : "+v"(a), "+v"(b));
#endif
}

// async global->LDS, 16B per lane. LDS dest is wave-uniform-base + lane*16;
// global src is per-lane (this is how the source-side swizzle is applied).
__device__ __forceinline__ void gload_lds16(const ushort_t* g, ushort_t* l) {
  __builtin_amdgcn_global_load_lds(
      (const __attribute__((address_space(1))) unsigned int*)g,
      (__attribute__((address_space(3))) unsigned int*)l, 16, 0, 0);
}

// ---------------------------------------------------------------------------
// Kernel 1: fused grouped conv (MFMA) + bias. R11 rewrite (was ~190us, ~9x
// over its ~21us roofline, optimized blind — never in top-5):
//  * yl LDS round-trip ELIMINATED: MFMA C-layout already gives 4 consecutive
//    outputs in each acc rg-quad (p for Q-branch via swapped operands, co
//    for K/V) -> direct bf16x4 (8B/lane) global stores. L2 write-combines:
//    the 4 q-chunks + lanes complete full lines within a few instructions.
//  * barriers per block: ~32 -> 7 (1 x-stage + 2 per branch).
//  * block-wide redbuf reduction (needed barriers) -> per-wave shuffle +
//    per-wave atomicAdd (4x atomics, ~49K total on 768 floats).
//  * LDS 47KB -> 37KB => 4 blocks/CU (was 3), 32 waves/CU.
// grid (pc=16, g*b=64), 256 thr.
// Q branch -> [B][C][P]; K/V branches -> [B][H][P][128].
// ---------------------------------------------------------------------------
__global__ __launch_bounds__(256) void conv_gn(
    const float* __restrict__ x,
    const float* __restrict__ wq, const float* __restrict__ wk, const float* __restrict__ wv,
    const float* __restrict__ bq, const float* __restrict__ bk, const float* __restrict__ bv,
    ushort_t* __restrict__ Qb, ushort_t* __restrict__ Kb, ushort_t* __restrict__ Vb,
    float* __restrict__ stats) {
  int pc = blockIdx.x;
  int gz = blockIdx.y;
  int b = gz & 7, g = gz >> 3;
  int tid = threadIdx.x, lane = tid & 63, wid = tid >> 6;
  int l15 = lane & 15, q = lane >> 4;

  __shared__ __align__(16) ushort_t xl[128 * 72];   // [p][f]
  __shared__ __align__(16) ushort_t wl[128 * 72];   // [co][f], one branch
  __shared__ float biasl[128];

  // stage x tile [64 f][128 p] f32 -> xl[p][f] bf16
  const float* xsrc = x + ((size_t)(b * 512 + g * 64)) * 2048 + pc * 128;
#pragma unroll
  for (int r = 0; r < 8; ++r) {
    int chunk = tid + 256 * r;
    int c = chunk >> 5, p4 = chunk & 31;
    float4 v = *(const float4*)&xsrc[(size_t)c * 2048 + p4 * 4];
    xl[(p4 * 4 + 0) * 72 + c] = f2bf(v.x);
    xl[(p4 * 4 + 1) * 72 + c] = f2bf(v.y);
    xl[(p4 * 4 + 2) * 72 + c] = f2bf(v.z);
    xl[(p4 * 4 + 3) * 72 + c] = f2bf(v.w);
  }
  __syncthreads();

  // resident B-frags (wave's 32 p-cols)
  bf16x8 Bx[2][2];
#pragma unroll
  for (int n2 = 0; n2 < 2; ++n2)
#pragma unroll
    for (int kk = 0; kk < 2; ++kk)
      Bx[n2][kk] = *(const bf16x8*)&xl[((wid * 2 + n2) * 16 + l15) * 72 + kk * 32 + q * 8];

  for (int br = 0; br < 3; ++br) {
    const float* w    = (br == 0) ? wq : ((br == 1) ? wk : wv);
    const float* bias = (br == 0) ? bq : ((br == 1) ? bk : bv);
    ushort_t* dst     = (br == 0) ? Qb : ((br == 1) ? Kb : Vb);
    __syncthreads();   // previous branch's wl consumers (Aw reads) done
    const float* wsrc = w + (size_t)g * 128 * 64;
#pragma unroll
    for (int r = 0; r < 8; ++r) {
      int idx = (tid + 256 * r) << 2;
      float4 v = *(const float4*)&wsrc[idx];
      int row = idx >> 6, f = idx & 63;
      bf16x4 wv4 = {(__bf16)v.x, (__bf16)v.y, (__bf16)v.z, (__bf16)v.w};
      *(bf16x4*)&wl[row * 72 + f] = wv4;
    }
    if (tid < 128) biasl[tid] = bias[g * 128 + tid];
    __syncthreads();   // wl visible

    for (int ngs = 0; ngs < 4; ++ngs) {
      int co0 = ngs * 32;
      bf16x8 Aw[2][2];
#pragma unroll
      for (int m = 0; m < 2; ++m)
#pragma unroll
        for (int kk = 0; kk < 2; ++kk)
          Aw[m][kk] = *(const bf16x8*)&wl[(co0 + m * 16 + l15) * 72 + kk * 32 + q * 8];
      // acc[a][c2]: br==0 (swapped): a = n2 (p-tile), c2 = mw (co-tile);
      //             br>=1:           a = m  (co),     c2 = n2 (p)
      f32x4 acc[2][2];
#pragma unroll
      for (int a = 0; a < 2; ++a)
#pragma unroll
        for (int c2 = 0; c2 < 2; ++c2) acc[a][c2] = (f32x4){0.f, 0.f, 0.f, 0.f};
      if (br == 0) {
#pragma unroll
        for (int kk = 0; kk < 2; ++kk)
#pragma unroll
          for (int n2 = 0; n2 < 2; ++n2)
#pragma unroll
            for (int mw = 0; mw < 2; ++mw)
              acc[n2][mw] = MFMA16(Bx[n2][kk], Aw[mw][kk], acc[n2][mw]);
      } else {
#pragma unroll
        for (int kk = 0; kk < 2; ++kk)
#pragma unroll
          for (int n2 = 0; n2 < 2; ++n2)
#pragma unroll
            for (int m = 0; m < 2; ++m)
              acc[m][n2] = MFMA16(Aw[m][kk], Bx[n2][kk], acc[m][n2]);
      }

      float s1 = 0.f, s2 = 0.f;
      if (br == 0) {   // C: col=l15=co_local, row=4q+rg=p_local
#pragma unroll
        for (int n2 = 0; n2 < 2; ++n2)
#pragma unroll
          for (int mw = 0; mw < 2; ++mw) {
            float bi = biasl[co0 + mw * 16 + l15];
#pragma unroll
            for (int rg = 0; rg < 4; ++rg) {
              float y = acc[n2][mw][rg] + bi;
              acc[n2][mw][rg] = y;
              s1 += y; s2 += y * y;
            }
          }
      } else {         // C: col=l15=p_local, row=4q+rg=co_local
#pragma unroll
        for (int m = 0; m < 2; ++m)
#pragma unroll
          for (int n2 = 0; n2 < 2; ++n2)
#pragma unroll
            for (int rg = 0; rg < 4; ++rg) {
              float y = acc[m][n2][rg] + biasl[co0 + m * 16 + 4 * q + rg];
              acc[m][n2][rg] = y;
              s1 += y; s2 += y * y;
            }
      }
      // per-wave reduce + per-wave atomic (no barriers needed)
#pragma unroll
      for (int mask = 32; mask >= 1; mask >>= 1) {
        s1 += __shfl_xor(s1, mask, 64);
        s2 += __shfl_xor(s2, mask, 64);
      }
      if (lane == 0) {
        int sidx = (br * 8 + b) * 32 + g * 4 + ngs;
        atomicAdd(&stats[2 * sidx], s1);
        atomicAdd(&stats[2 * sidx + 1], s2);
      }

      // direct bf16x4 global stores (rg-quad is contiguous in memory)
      if (br == 0) {   // Qb[B][C][P]: row co, 4 consecutive p per quad
#pragma unroll
        for (int n2 = 0; n2 < 2; ++n2)
#pragma unroll
          for (int mw = 0; mw < 2; ++mw) {
            bf16x4 pk = {(__bf16)acc[n2][mw][0], (__bf16)acc[n2][mw][1],
                         (__bf16)acc[n2][mw][2], (__bf16)acc[n2][mw][3]};
            int co = co0 + mw * 16 + l15;
            int p  = pc * 128 + (wid * 2 + n2) * 16 + 4 * q;
            *(bf16x4*)&dst[((size_t)(b * 1024 + g * 128 + co)) * 2048 + p] = pk;
          }
      } else {         // Kb/Vb[B][H][P][128]: row p, 4 consecutive co per quad
#pragma unroll
        for (int m = 0; m < 2; ++m)
#pragma unroll
          for (int n2 = 0; n2 < 2; ++n2) {
            bf16x4 pk = {(__bf16)acc[m][n2][0], (__bf16)acc[m][n2][1],
                         (__bf16)acc[m][n2][2], (__bf16)acc[m][n2][3]};
            int p  = pc * 128 + (wid * 2 + n2) * 16 + l15;
            int co = co0 + m * 16 + 4 * q;
            *(bf16x4*)&dst[((size_t)(b * 8 + g) * 2048 + p) * 128 + co] = pk;
          }
      }
    }
  }
}

// ---------------------------------------------------------------------------
// Kernel 2: in-place GroupNorm affine + LeakyReLU over the 3 contiguous bufs.
// grid-stride (2048 blocks x 12 iters).
// ---------------------------------------------------------------------------
__global__ __launch_bounds__(256) void gn_apply(
    ushort_t* __restrict__ buf, const float* __restrict__ stats,
    const float* __restrict__ gw1, const float* __restrict__ gb1,
    const float* __restrict__ gw2, const float* __restrict__ gb2,
    const float* __restrict__ gw3, const float* __restrict__ gb3) {
  const unsigned NQ = 16777216u;
  unsigned base = blockIdx.x * 256 + threadIdx.x;   // 524288 threads
  for (int itn = 0; itn < 12; ++itn) {
    unsigned gid = base + (unsigned)itn * 524288u;
    unsigned e = gid * 8;
    int br; unsigned local;
    if (e < NQ)            { br = 0; local = e; }
    else if (e < 2u * NQ)  { br = 1; local = e - NQ; }
    else                   { br = 2; local = e - 2u * NQ; }
    int b, c0;
    if (br == 0) { b = local >> 21; c0 = (local >> 11) & 1023; }
    else {
      int cih = local & 127; int h = (local >> 18) & 7;
      b = local >> 21; c0 = h * 128 + cih;
    }
    int ng = c0 >> 5;
    const float* gw = (br == 0) ? gw1 : ((br == 1) ? gw2 : gw3);
    const float* gb = (br == 0) ? gb1 : ((br == 1) ? gb2 : gb3);
    int sidx = (br * 8 + b) * 32 + ng;
    float mean = stats[2 * sidx] * (1.f / 65536.f);
    float var  = stats[2 * sidx + 1] * (1.f / 65536.f) - mean * mean;
    float rstd = rsqrtf(var + 1e-5f);
    uint4 d = *(uint4*)&buf[(size_t)e];
    ushort_t* pu = (ushort_t*)&d;
#pragma unroll
    for (int i = 0; i < 8; ++i) {
      int ci = (br == 0) ? c0 : (c0 + i);
      float a = rstd * gw[ci];
      float b2 = gb[ci] - mean * a;
      float yn = fmaf(bf2f(pu[i]), a, b2);
      yn = (yn >= 0.f) ? yn : 0.1f * yn;
      pu[i] = f2bf(yn);
    }
    *(uint4*)&buf[(size_t)e] = d;
  }
}

// ---------------------------------------------------------------------------
// Kernel 3: flash attention, 32x32x16 MFMA, S^T formulation.  (EXACT R9/R4
// 174us version — R10's x2 j-unroll spilled (+16MB scratch writes) and
// regressed to 232us; reverted byte-for-byte.)
// flashQ=K-branch [B,H,P,128] (i), flashK=V-branch [B,H,P,128] (j),
// flashV=Q-branch [B,C,P] (c rows, p=j cols).
// Block: i-tile 256 (4 waves x 64 i = 2 n-tiles), grid (8,64) + XCD remap.
//  * T12 register-P via cvt_pk + permlane32_swap.
//  * XCD remap: lin = bx + 8*by; it=(lin>>3)&7, bh=(lin&7)+8*(lin>>6)
//    -> XCD = bh&7 (FETCH 285->51MB).
//  * T5 setprio around MFMA clusters; defer-max; exp2 softmax.
//  * launch_bounds(256,2): VGPR 128+AGPR 128 = at the register-file cap.
//    DO NOT unroll the j-loop or lower the bound: both spill (R7/R10).
// LDS 32 KB, 2 blocks/CU.
// ---------------------------------------------------------------------------
__global__ __launch_bounds__(256, 2) void attn(
    const ushort_t* __restrict__ Qb, const ushort_t* __restrict__ Kb,
    const ushort_t* __restrict__ Vb, float* __restrict__ out) {
  __shared__ __align__(16) ushort_t fKs[2][32 * 128];   // [j][d] linear, 2x8192 B
  __shared__ __align__(16) ushort_t Vs[2][128 * 32];    // [c][j] linear, 2x8192 B

  int lin = blockIdx.x + 8 * blockIdx.y;           // XCD = lin % 8
  int it = (lin >> 3) & 7;
  int bh = (lin & 7) + 8 * (lin >> 6);             // XCD = bh & 7
  int b = bh >> 3, h = bh & 7;
  int tid = threadIdx.x, lane = tid & 63, wid = tid >> 6;
  int l31 = lane & 31, q2 = lane >> 5;
  // scale*log2(e): softmax in exp2 domain
  const float sl = 0.08838834764831845f * 1.4426950408889634f;

  // resident fQ B-frags: B[k=d][n=i], n-col = l31 -> row i (one-time load)
  bf16x8 Bq[2][8];
#pragma unroll
  for (int nt = 0; nt < 2; ++nt) {
    const ushort_t* fQp =
        Kb + ((size_t)bh * 2048 + it * 256 + wid * 64 + nt * 32 + l31) * 128 + q2 * 8;
#pragma unroll
    for (int dc = 0; dc < 8; ++dc) Bq[nt][dc] = *(const bf16x8*)&fQp[dc * 16];
  }

  float m2[2], l_i[2];
  m2[0] = m2[1] = -3e38f;
  l_i[0] = l_i[1] = 0.f;
  f32x16 O[4][2];
#pragma unroll
  for (int mt = 0; mt < 4; ++mt)
#pragma unroll
    for (int nt = 0; nt < 2; ++nt) O[mt][nt] = (f32x16)(0.f);

  const ushort_t* fKg = Vb + (size_t)bh * 2048 * 128;
  const ushort_t* fVg = Qb + ((size_t)(b * 1024 + h * 128)) * 2048;

  // ---- staging: 512 16B-units per tensor-tile; each thread issues 2+2.
  // LDS is linear in unit index n (wave-uniform base + lane*16); the XOR
  // swizzle is applied to the unit index on the GLOBAL side.
#define STAGE(JT, NB)                                                          \
  do {                                                                         \
    _Pragma("unroll")                                                          \
    for (int r = 0; r < 2; ++r) {                                              \
      int n = tid + 256 * r;                                                   \
      int kr = n >> 4, ku = (n & 15) ^ (kr & 7);                               \
      gload_lds16(fKg + (size_t)(JT) * 4096 + kr * 128 + ku * 8,               \
                  &fKs[NB][n * 8]);                                            \
      int vr = n >> 2, vu = (n & 3) ^ ((vr >> 1) & 3);                         \
      gload_lds16(fVg + (size_t)vr * 2048 + (JT) * 32 + vu * 8,                \
                  &Vs[NB][n * 8]);                                             \
    }                                                                          \
  } while (0)

  STAGE(0, 0);
  __syncthreads();   // vmcnt(0) drain + barrier: tile 0 visible
  int cur = 0;

  for (int jt = 0; jt < 64; ++jt) {
    if (jt < 63) STAGE(jt + 1, cur ^ 1);   // async prefetch into idle buffer

    // S^T = fK . fQ^T : 8 swizzled A-reads, 16 MFMAs
    f32x16 ST[2];
    ST[0] = (f32x16)(0.f);
    ST[1] = (f32x16)(0.f);
    __builtin_amdgcn_s_setprio(1);
#pragma unroll
    for (int dc = 0; dc < 8; ++dc) {
      int up = (dc * 2 + q2) ^ (l31 & 7);
      bf16x8 Ak = *(const bf16x8*)&fKs[cur][l31 * 128 + up * 8];
      ST[0] = MFMA32(Ak, Bq[0][dc], ST[0]);
      ST[1] = MFMA32(Ak, Bq[1][dc], ST[1]);
    }
    __builtin_amdgcn_s_setprio(0);

    // online softmax over j; lane covers i (j split across q2).
    // P -> bf16 MFMA B-frags IN REGISTER via cvt_pk + permlane32_swap.
    bf16x8 Bp[2][2];   // [nt][jc]
#pragma unroll
    for (int nt = 0; nt < 2; ++nt) {
      float vmax = ST[nt][0];
#pragma unroll
      for (int rg = 1; rg < 16; ++rg) vmax = fmaxf(vmax, ST[nt][rg]);
      float v2 = vmax * sl;
      v2 = fmaxf(v2, __shfl_xor(v2, 32, 64));
      float al = 1.f;
      bool need = !__all(v2 <= m2[nt] + 8.f);   // defer-max: wave-uniform
      if (need) {
        float mn2 = fmaxf(m2[nt], v2);
        al = __builtin_amdgcn_exp2f(m2[nt] - mn2);
        m2[nt] = mn2;
      }
      float mn = m2[nt];
      float p16[16];
      float rs = 0.f;
#pragma unroll
      for (int rg = 0; rg < 16; ++rg) {
        p16[rg] = __builtin_amdgcn_exp2f(fmaf(ST[nt][rg], sl, -mn));
        rs += p16[rg];
      }
      rs += __shfl_xor(rs, 32, 64);
      l_i[nt] = l_i[nt] * al + rs;
      if (need) {   // O rescale only when running max moved (i on lanes)
#pragma unroll
        for (int mt = 0; mt < 4; ++mt)
#pragma unroll
          for (int rg = 0; rg < 16; ++rg) O[mt][nt][rg] *= al;
      }
#pragma unroll
      for (int jc = 0; jc < 2; ++jc) {
        unsigned pa, pb, pc_, pd;
        asm("v_cvt_pk_bf16_f32 %0, %1, %2"
            : "=v"(pa) : "v"(p16[jc * 8 + 0]), "v"(p16[jc * 8 + 1]));
        asm("v_cvt_pk_bf16_f32 %0, %1, %2"
            : "=v"(pc_) : "v"(p16[jc * 8 + 2]), "v"(p16[jc * 8 + 3]));
        asm("v_cvt_pk_bf16_f32 %0, %1, %2"
            : "=v"(pb) : "v"(p16[jc * 8 + 4]), "v"(p16[jc * 8 + 5]));
        asm("v_cvt_pk_bf16_f32 %0, %1, %2"
            : "=v"(pd) : "v"(p16[jc * 8 + 6]), "v"(p16[jc * 8 + 7]));
        plswap(pa, pb);
        plswap(pc_, pd);
        union { unsigned u[4]; bf16x8 v; } fr;
        fr.u[0] = pa; fr.u[1] = pc_; fr.u[2] = pb; fr.u[3] = pd;
        Bp[nt][jc] = fr.v;
      }
    }

    // O^T += V . P^T : 8 swizzled V-reads, 16 MFMAs (P in registers)
    __builtin_amdgcn_s_setprio(1);
#pragma unroll
    for (int jc = 0; jc < 2; ++jc) {
#pragma unroll
      for (int mt = 0; mt < 4; ++mt) {
        int row = mt * 32 + l31;
        int up = (jc * 2 + q2) ^ ((row >> 1) & 3);
        bf16x8 Av = *(const bf16x8*)&Vs[cur][row * 32 + up * 8];
        O[mt][0] = MFMA32(Av, Bp[0][jc], O[mt][0]);
        O[mt][1] = MFMA32(Av, Bp[1][jc], O[mt][1]);
      }
    }
    __builtin_amdgcn_s_setprio(0);
    __syncthreads();   // single barrier: prefetch complete + all reads done
    cur ^= 1;
  }
#undef STAGE

  // epilogue: i on lanes -> direct coalesced stores
  float linv[2];
  linv[0] = 1.f / l_i[0];
  linv[1] = 1.f / l_i[1];
#pragma unroll
  for (int mt = 0; mt < 4; ++mt)
#pragma unroll
    for (int nt = 0; nt < 2; ++nt) {
      float* obase = out + ((size_t)(b * 1024 + h * 128 + mt * 32)) * 2048 +
                     it * 256 + wid * 64 + nt * 32 + l31;
#pragma unroll
      for (int rg = 0; rg < 16; ++rg) {
        int c = (rg & 3) + 8 * (rg >> 2) + 4 * q2;
        obase[(size_t)c * 2048] = O[mt][nt][rg] * linv[nt];
      }
    }
}

// ---------------------------------------------------------------------------
extern "C" void kernel_launch(void* const* d_in, const int* in_sizes, int n_in,
                              void* d_out, int out_size, void* d_ws, size_t ws_size,
                              hipStream_t stream) {
  const float* x   = (const float*)d_in[0];
  const float* wq  = (const float*)d_in[1];
  const float* bq  = (const float*)d_in[2];
  const float* gw1 = (const float*)d_in[3];
  const float* gb1 = (const float*)d_in[4];
  const float* wk  = (const float*)d_in[5];
  const float* bk  = (const float*)d_in[6];
  const float* gw2 = (const float*)d_in[7];
  const float* gb2 = (const float*)d_in[8];
  const float* wv  = (const float*)d_in[9];
  const float* bv  = (const float*)d_in[10];
  const float* gw3 = (const float*)d_in[11];
  const float* gb3 = (const float*)d_in[12];
  float* out = (float*)d_out;
  char* ws = (char*)d_ws;

  ushort_t* Qb = (ushort_t*)(ws);               // 33,554,432 B  [B,C,P] bf16
  ushort_t* Kb = (ushort_t*)(ws + 33554432);    // 33,554,432 B  [B,H,P,128] bf16
  ushort_t* Vb = (ushort_t*)(ws + 67108864);    // 33,554,432 B  [B,H,P,128] bf16
  float* stats = (float*)(ws + 100663296);      // 768 groups x {s1,s2}

  hipMemsetAsync(stats, 0, 1536 * sizeof(float), stream);
  conv_gn<<<dim3(16, 64), 256, 0, stream>>>(x, wq, wk, wv, bq, bk, bv,
                                            Qb, Kb, Vb, stats);
  gn_apply<<<2048, 256, 0, stream>>>(Qb, stats, gw1, gb1, gw2, gb2, gw3, gb3);
  attn<<<dim3(8, 64), 256, 0, stream>>>(Qb, Kb, Vb, out);
}

// Round 7
// 420.789 us; speedup vs baseline: 1.1367x; 1.0428x over previous
//
#include <hip/hip_runtime.h>

typedef unsigned short ushort_t;
typedef float  f32x4   __attribute__((ext_vector_type(4)));
typedef float  f32x16  __attribute__((ext_vector_type(16)));
typedef __bf16 bf16x4  __attribute__((ext_vector_type(4)));
typedef __bf16 bf16x8  __attribute__((ext_vector_type(8)));
typedef unsigned uint2v __attribute__((ext_vector_type(2)));

#define MFMA16(a,b,c) __builtin_amdgcn_mfma_f32_16x16x32_bf16((a),(b),(c),0,0,0)
#define MFMA32(a,b,c) __builtin_amdgcn_mfma_f32_32x32x16_bf16((a),(b),(c),0,0,0)

__device__ __forceinline__ ushort_t f2bf(float f) {
  union { float f; unsigned u; } v; v.f = f;
  unsigned u = v.u;
  unsigned r = u + 0x7FFFu + ((u >> 16) & 1u);   // round-to-nearest-even
  return (ushort_t)(r >> 16);
}
__device__ __forceinline__ float bf2f(ushort_t s) {
  union { unsigned u; float f; } v; v.u = ((unsigned)s) << 16;
  return v.f;
}

// swap lanes 32-63 of a with lanes 0-31 of b (v_permlane32_swap_b32)
__device__ __forceinline__ void plswap(unsigned& a, unsigned& b) {
#if __has_builtin(__builtin_amdgcn_permlane32_swap)
  uint2v r = __builtin_amdgcn_permlane32_swap(a, b, false, false);
  a = r[0]; b = r[1];
#else
  asm("v_permlane32_swap_b32 %0, %1" : "+v"(a), "+v"(b));
#endif
}

// async global->LDS, 16B per lane. LDS dest is wave-uniform-base + lane*16;
// global src is per-lane (this is how the source-side swizzle is applied).
__device__ __forceinline__ void gload_lds16(const ushort_t* g, ushort_t* l) {
  __builtin_amdgcn_global_load_lds(
      (const __attribute__((address_space(1))) unsigned int*)g,
      (__attribute__((address_space(3))) unsigned int*)l, 16, 0, 0);
}

// ---------------------------------------------------------------------------
// Kernel 1: fused grouped conv (MFMA) + bias. R12:
// R6 post-mortem: direct 8B stores cost +32us (32B-chunk sector waste on
// 100MB of writes) -> KEEP the R4 yl-staged fully-coalesced uint4 stores.
// R4's ~193us is NOT barrier- or store-bound; hypothesis: latency with too
// little independent work (1024 long 3-branch blocks, 3 blocks/CU).
//  * branch -> gridDim.z: 3072 blocks, each 3x shorter, independent.
//    (x re-read per branch: +67MB, but x total = 33.5MB -> L3-resident.)
//  * yl UNIONED into xl: Bx is register-resident after the initial frag
//    read, xl dead after -> reuse as yl. LDS 47 -> 37KB = 4 blocks/CU.
//  * stats: per-wave shuffle -> redbuf write piggybacked on the existing
//    yl barrier; ONE atomicAdd pair per block per ngs. 10 barriers/block.
// grid (pc=16, g*b=64, br=3), 256 thr.
// Q branch -> [B][C][P]; K/V branches -> [B][H][P][128].
// ---------------------------------------------------------------------------
__global__ __launch_bounds__(256) void conv_gn(
    const float* __restrict__ x,
    const float* __restrict__ wq, const float* __restrict__ wk, const float* __restrict__ wv,
    const float* __restrict__ bq, const float* __restrict__ bk, const float* __restrict__ bv,
    ushort_t* __restrict__ Qb, ushort_t* __restrict__ Kb, ushort_t* __restrict__ Vb,
    float* __restrict__ stats) {
  int pc = blockIdx.x;
  int gz = blockIdx.y;
  int br = blockIdx.z;
  int b = gz & 7, g = gz >> 3;
  int tid = threadIdx.x, lane = tid & 63, wid = tid >> 6;
  int l15 = lane & 15, q = lane >> 4;

  __shared__ __align__(16) ushort_t xl[128 * 72];   // [p][f]; reused as yl
  __shared__ __align__(16) ushort_t wl[128 * 72];   // [co][f]
  __shared__ float biasl[128];
  __shared__ float redbuf[8];
  ushort_t* yl = xl;   // xl dead after Bx frag reads

  // stage x tile [64 f][128 p] f32 -> xl[p][f] bf16
  const float* xsrc = x + ((size_t)(b * 512 + g * 64)) * 2048 + pc * 128;
#pragma unroll
  for (int r = 0; r < 8; ++r) {
    int chunk = tid + 256 * r;
    int c = chunk >> 5, p4 = chunk & 31;
    float4 v = *(const float4*)&xsrc[(size_t)c * 2048 + p4 * 4];
    xl[(p4 * 4 + 0) * 72 + c] = f2bf(v.x);
    xl[(p4 * 4 + 1) * 72 + c] = f2bf(v.y);
    xl[(p4 * 4 + 2) * 72 + c] = f2bf(v.z);
    xl[(p4 * 4 + 3) * 72 + c] = f2bf(v.w);
  }

  const float* w    = (br == 0) ? wq : ((br == 1) ? wk : wv);
  const float* bias = (br == 0) ? bq : ((br == 1) ? bk : bv);
  ushort_t* dst     = (br == 0) ? Qb : ((br == 1) ? Kb : Vb);

  __syncthreads();   // xl visible

  // resident B-frags (wave's 32 p-cols); xl dead after this
  bf16x8 Bx[2][2];
#pragma unroll
  for (int n2 = 0; n2 < 2; ++n2)
#pragma unroll
    for (int kk = 0; kk < 2; ++kk)
      Bx[n2][kk] = *(const bf16x8*)&xl[((wid * 2 + n2) * 16 + l15) * 72 + kk * 32 + q * 8];

  // stage w [128 co][64 f] f32 -> wl bf16 (coalesced float4)
  const float* wsrc = w + (size_t)g * 128 * 64;
#pragma unroll
  for (int r = 0; r < 8; ++r) {
    int idx = (tid + 256 * r) << 2;
    float4 v = *(const float4*)&wsrc[idx];
    int row = idx >> 6, f = idx & 63;
    bf16x4 wv4 = {(__bf16)v.x, (__bf16)v.y, (__bf16)v.z, (__bf16)v.w};
    *(bf16x4*)&wl[row * 72 + f] = wv4;
  }
  if (tid < 128) biasl[tid] = bias[g * 128 + tid];
  __syncthreads();   // wl visible AND all Bx reads done (xl reusable)

  for (int ngs = 0; ngs < 4; ++ngs) {
    int co0 = ngs * 32;
    bf16x8 Aw[2][2];
#pragma unroll
    for (int m = 0; m < 2; ++m)
#pragma unroll
      for (int kk = 0; kk < 2; ++kk)
        Aw[m][kk] = *(const bf16x8*)&wl[(co0 + m * 16 + l15) * 72 + kk * 32 + q * 8];
    // acc[a][c2]: br==0 (swapped): a = n2 (p-tile), c2 = mw (co-tile);
    //             br>=1:           a = m  (co),     c2 = n2 (p)
    f32x4 acc[2][2];
#pragma unroll
    for (int a = 0; a < 2; ++a)
#pragma unroll
      for (int c2 = 0; c2 < 2; ++c2) acc[a][c2] = (f32x4){0.f, 0.f, 0.f, 0.f};
    if (br == 0) {
#pragma unroll
      for (int kk = 0; kk < 2; ++kk)
#pragma unroll
        for (int n2 = 0; n2 < 2; ++n2)
#pragma unroll
          for (int mw = 0; mw < 2; ++mw)
            acc[n2][mw] = MFMA16(Bx[n2][kk], Aw[mw][kk], acc[n2][mw]);
    } else {
#pragma unroll
      for (int kk = 0; kk < 2; ++kk)
#pragma unroll
        for (int n2 = 0; n2 < 2; ++n2)
#pragma unroll
          for (int m = 0; m < 2; ++m)
            acc[m][n2] = MFMA16(Aw[m][kk], Bx[n2][kk], acc[m][n2]);
    }

    float s1 = 0.f, s2 = 0.f;
    if (br == 0) {   // C: col=l15=co_local, row=4q+rg=p_local
#pragma unroll
      for (int n2 = 0; n2 < 2; ++n2)
#pragma unroll
        for (int mw = 0; mw < 2; ++mw) {
          float bi = biasl[co0 + mw * 16 + l15];
#pragma unroll
          for (int rg = 0; rg < 4; ++rg) {
            float y = acc[n2][mw][rg] + bi;
            acc[n2][mw][rg] = y;
            s1 += y; s2 += y * y;
          }
        }
    } else {         // C: col=l15=p_local, row=4q+rg=co_local
#pragma unroll
      for (int m = 0; m < 2; ++m)
#pragma unroll
        for (int n2 = 0; n2 < 2; ++n2)
#pragma unroll
          for (int rg = 0; rg < 4; ++rg) {
            float y = acc[m][n2][rg] + biasl[co0 + m * 16 + 4 * q + rg];
            acc[m][n2][rg] = y;
            s1 += y; s2 += y * y;
          }
    }
#pragma unroll
    for (int mask = 32; mask >= 1; mask >>= 1) {
      s1 += __shfl_xor(s1, mask, 64);
      s2 += __shfl_xor(s2, mask, 64);
    }
    if (lane == 0) { redbuf[wid * 2] = s1; redbuf[wid * 2 + 1] = s2; }

    // stage to yl (coalescing buffer; layouts match final memory order)
    if (br == 0) {   // yl: [32 c][136 p]; row = co_local (l15), cols = p (regs)
#pragma unroll
      for (int n2 = 0; n2 < 2; ++n2)
#pragma unroll
        for (int mw = 0; mw < 2; ++mw) {
          bf16x4 pk = {(__bf16)acc[n2][mw][0], (__bf16)acc[n2][mw][1],
                       (__bf16)acc[n2][mw][2], (__bf16)acc[n2][mw][3]};
          *(bf16x4*)&yl[(mw * 16 + l15) * 136 + (wid * 2 + n2) * 16 + 4 * q] = pk;
        }
    } else {         // yl: [128 p][40 c]; row = p (l15), cols = c (regs)
#pragma unroll
      for (int m = 0; m < 2; ++m)
#pragma unroll
        for (int n2 = 0; n2 < 2; ++n2) {
          bf16x4 pk = {(__bf16)acc[m][n2][0], (__bf16)acc[m][n2][1],
                       (__bf16)acc[m][n2][2], (__bf16)acc[m][n2][3]};
          *(bf16x4*)&yl[((wid * 2 + n2) * 16 + l15) * 40 + m * 16 + 4 * q] = pk;
        }
    }
    __syncthreads();   // yl + redbuf visible

    // fully-coalesced uint4 global stores (1KB/instr per wave)
    if (br == 0) {
#pragma unroll
      for (int r = 0; r < 2; ++r) {
        int chunk = tid + 256 * r;
        int row = chunk >> 4, ch = chunk & 15;
        *(uint4*)&dst[((size_t)(b * 1024 + g * 128 + co0 + row)) * 2048 + pc * 128 + ch * 8] =
            *(const uint4*)&yl[row * 136 + ch * 8];
      }
    } else {
#pragma unroll
      for (int r = 0; r < 2; ++r) {
        int chunk = tid + 256 * r;
        int row = chunk >> 2, ch = chunk & 3;
        *(uint4*)&dst[((size_t)(b * 8 + g) * 2048 + pc * 128 + row) * 128 + co0 + ch * 8] =
            *(const uint4*)&yl[row * 40 + ch * 8];
      }
    }
    if (tid == 0) {
      float S1 = redbuf[0] + redbuf[2] + redbuf[4] + redbuf[6];
      float S2 = redbuf[1] + redbuf[3] + redbuf[5] + redbuf[7];
      int sidx = (br * 8 + b) * 32 + g * 4 + ngs;
      atomicAdd(&stats[2 * sidx], S1);
      atomicAdd(&stats[2 * sidx + 1], S2);
    }
    __syncthreads();   // yl/redbuf reusable
  }
}

// ---------------------------------------------------------------------------
// Kernel 2: in-place GroupNorm affine + LeakyReLU over the 3 contiguous bufs.
// grid-stride (2048 blocks x 12 iters).
// ---------------------------------------------------------------------------
__global__ __launch_bounds__(256) void gn_apply(
    ushort_t* __restrict__ buf, const float* __restrict__ stats,
    const float* __restrict__ gw1, const float* __restrict__ gb1,
    const float* __restrict__ gw2, const float* __restrict__ gb2,
    const float* __restrict__ gw3, const float* __restrict__ gb3) {
  const unsigned NQ = 16777216u;
  unsigned base = blockIdx.x * 256 + threadIdx.x;   // 524288 threads
  for (int itn = 0; itn < 12; ++itn) {
    unsigned gid = base + (unsigned)itn * 524288u;
    unsigned e = gid * 8;
    int br; unsigned local;
    if (e < NQ)            { br = 0; local = e; }
    else if (e < 2u * NQ)  { br = 1; local = e - NQ; }
    else                   { br = 2; local = e - 2u * NQ; }
    int b, c0;
    if (br == 0) { b = local >> 21; c0 = (local >> 11) & 1023; }
    else {
      int cih = local & 127; int h = (local >> 18) & 7;
      b = local >> 21; c0 = h * 128 + cih;
    }
    int ng = c0 >> 5;
    const float* gw = (br == 0) ? gw1 : ((br == 1) ? gw2 : gw3);
    const float* gb = (br == 0) ? gb1 : ((br == 1) ? gb2 : gb3);
    int sidx = (br * 8 + b) * 32 + ng;
    float mean = stats[2 * sidx] * (1.f / 65536.f);
    float var  = stats[2 * sidx + 1] * (1.f / 65536.f) - mean * mean;
    float rstd = rsqrtf(var + 1e-5f);
    uint4 d = *(uint4*)&buf[(size_t)e];
    ushort_t* pu = (ushort_t*)&d;
#pragma unroll
    for (int i = 0; i < 8; ++i) {
      int ci = (br == 0) ? c0 : (c0 + i);
      float a = rstd * gw[ci];
      float b2 = gb[ci] - mean * a;
      float yn = fmaf(bf2f(pu[i]), a, b2);
      yn = (yn >= 0.f) ? yn : 0.1f * yn;
      pu[i] = f2bf(yn);
    }
    *(uint4*)&buf[(size_t)e] = d;
  }
}

// ---------------------------------------------------------------------------
// Kernel 3: flash attention, 32x32x16 MFMA, S^T formulation. (EXACT R4/R6
// 172us version — do not touch: register file at cap; j-unroll spills.)
// flashQ=K-branch [B,H,P,128] (i), flashK=V-branch [B,H,P,128] (j),
// flashV=Q-branch [B,C,P] (c rows, p=j cols).
// Block: i-tile 256 (4 waves x 64 i = 2 n-tiles), grid (8,64) + XCD remap.
//  * T12 register-P via cvt_pk + permlane32_swap.
//  * XCD remap: lin = bx + 8*by; it=(lin>>3)&7, bh=(lin&7)+8*(lin>>6)
//    -> XCD = bh&7 (FETCH 285->51MB).
//  * T5 setprio around MFMA clusters; defer-max; exp2 softmax.
//  * launch_bounds(256,2): VGPR 128+AGPR 128 = at the register-file cap.
// LDS 32 KB, 2 blocks/CU.
// ---------------------------------------------------------------------------
__global__ __launch_bounds__(256, 2) void attn(
    const ushort_t* __restrict__ Qb, const ushort_t* __restrict__ Kb,
    const ushort_t* __restrict__ Vb, float* __restrict__ out) {
  __shared__ __align__(16) ushort_t fKs[2][32 * 128];   // [j][d] linear, 2x8192 B
  __shared__ __align__(16) ushort_t Vs[2][128 * 32];    // [c][j] linear, 2x8192 B

  int lin = blockIdx.x + 8 * blockIdx.y;           // XCD = lin % 8
  int it = (lin >> 3) & 7;
  int bh = (lin & 7) + 8 * (lin >> 6);             // XCD = bh & 7
  int b = bh >> 3, h = bh & 7;
  int tid = threadIdx.x, lane = tid & 63, wid = tid >> 6;
  int l31 = lane & 31, q2 = lane >> 5;
  // scale*log2(e): softmax in exp2 domain
  const float sl = 0.08838834764831845f * 1.4426950408889634f;

  // resident fQ B-frags: B[k=d][n=i], n-col = l31 -> row i (one-time load)
  bf16x8 Bq[2][8];
#pragma unroll
  for (int nt = 0; nt < 2; ++nt) {
    const ushort_t* fQp =
        Kb + ((size_t)bh * 2048 + it * 256 + wid * 64 + nt * 32 + l31) * 128 + q2 * 8;
#pragma unroll
    for (int dc = 0; dc < 8; ++dc) Bq[nt][dc] = *(const bf16x8*)&fQp[dc * 16];
  }

  float m2[2], l_i[2];
  m2[0] = m2[1] = -3e38f;
  l_i[0] = l_i[1] = 0.f;
  f32x16 O[4][2];
#pragma unroll
  for (int mt = 0; mt < 4; ++mt)
#pragma unroll
    for (int nt = 0; nt < 2; ++nt) O[mt][nt] = (f32x16)(0.f);

  const ushort_t* fKg = Vb + (size_t)bh * 2048 * 128;
  const ushort_t* fVg = Qb + ((size_t)(b * 1024 + h * 128)) * 2048;

  // ---- staging: 512 16B-units per tensor-tile; each thread issues 2+2.
  // LDS is linear in unit index n (wave-uniform base + lane*16); the XOR
  // swizzle is applied to the unit index on the GLOBAL side.
#define STAGE(JT, NB)                                                          \
  do {                                                                         \
    _Pragma("unroll")                                                          \
    for (int r = 0; r < 2; ++r) {                                              \
      int n = tid + 256 * r;                                                   \
      int kr = n >> 4, ku = (n & 15) ^ (kr & 7);                               \
      gload_lds16(fKg + (size_t)(JT) * 4096 + kr * 128 + ku * 8,               \
                  &fKs[NB][n * 8]);                                            \
      int vr = n >> 2, vu = (n & 3) ^ ((vr >> 1) & 3);                         \
      gload_lds16(fVg + (size_t)vr * 2048 + (JT) * 32 + vu * 8,                \
                  &Vs[NB][n * 8]);                                             \
    }                                                                          \
  } while (0)

  STAGE(0, 0);
  __syncthreads();   // vmcnt(0) drain + barrier: tile 0 visible
  int cur = 0;

  for (int jt = 0; jt < 64; ++jt) {
    if (jt < 63) STAGE(jt + 1, cur ^ 1);   // async prefetch into idle buffer

    // S^T = fK . fQ^T : 8 swizzled A-reads, 16 MFMAs
    f32x16 ST[2];
    ST[0] = (f32x16)(0.f);
    ST[1] = (f32x16)(0.f);
    __builtin_amdgcn_s_setprio(1);
#pragma unroll
    for (int dc = 0; dc < 8; ++dc) {
      int up = (dc * 2 + q2) ^ (l31 & 7);
      bf16x8 Ak = *(const bf16x8*)&fKs[cur][l31 * 128 + up * 8];
      ST[0] = MFMA32(Ak, Bq[0][dc], ST[0]);
      ST[1] = MFMA32(Ak, Bq[1][dc], ST[1]);
    }
    __builtin_amdgcn_s_setprio(0);

    // online softmax over j; lane covers i (j split across q2).
    // P -> bf16 MFMA B-frags IN REGISTER via cvt_pk + permlane32_swap.
    bf16x8 Bp[2][2];   // [nt][jc]
#pragma unroll
    for (int nt = 0; nt < 2; ++nt) {
      float vmax = ST[nt][0];
#pragma unroll
      for (int rg = 1; rg < 16; ++rg) vmax = fmaxf(vmax, ST[nt][rg]);
      float v2 = vmax * sl;
      v2 = fmaxf(v2, __shfl_xor(v2, 32, 64));
      float al = 1.f;
      bool need = !__all(v2 <= m2[nt] + 8.f);   // defer-max: wave-uniform
      if (need) {
        float mn2 = fmaxf(m2[nt], v2);
        al = __builtin_amdgcn_exp2f(m2[nt] - mn2);
        m2[nt] = mn2;
      }
      float mn = m2[nt];
      float p16[16];
      float rs = 0.f;
#pragma unroll
      for (int rg = 0; rg < 16; ++rg) {
        p16[rg] = __builtin_amdgcn_exp2f(fmaf(ST[nt][rg], sl, -mn));
        rs += p16[rg];
      }
      rs += __shfl_xor(rs, 32, 64);
      l_i[nt] = l_i[nt] * al + rs;
      if (need) {   // O rescale only when running max moved (i on lanes)
#pragma unroll
        for (int mt = 0; mt < 4; ++mt)
#pragma unroll
          for (int rg = 0; rg < 16; ++rg) O[mt][nt][rg] *= al;
      }
#pragma unroll
      for (int jc = 0; jc < 2; ++jc) {
        unsigned pa, pb, pc_, pd;
        asm("v_cvt_pk_bf16_f32 %0, %1, %2"
            : "=v"(pa) : "v"(p16[jc * 8 + 0]), "v"(p16[jc * 8 + 1]));
        asm("v_cvt_pk_bf16_f32 %0, %1, %2"
            : "=v"(pc_) : "v"(p16[jc * 8 + 2]), "v"(p16[jc * 8 + 3]));
        asm("v_cvt_pk_bf16_f32 %0, %1, %2"
            : "=v"(pb) : "v"(p16[jc * 8 + 4]), "v"(p16[jc * 8 + 5]));
        asm("v_cvt_pk_bf16_f32 %0, %1, %2"
            : "=v"(pd) : "v"(p16[jc * 8 + 6]), "v"(p16[jc * 8 + 7]));
        plswap(pa, pb);
        plswap(pc_, pd);
        union { unsigned u[4]; bf16x8 v; } fr;
        fr.u[0] = pa; fr.u[1] = pc_; fr.u[2] = pb; fr.u[3] = pd;
        Bp[nt][jc] = fr.v;
      }
    }

    // O^T += V . P^T : 8 swizzled V-reads, 16 MFMAs (P in registers)
    __builtin_amdgcn_s_setprio(1);
#pragma unroll
    for (int jc = 0; jc < 2; ++jc) {
#pragma unroll
      for (int mt = 0; mt < 4; ++mt) {
        int row = mt * 32 + l31;
        int up = (jc * 2 + q2) ^ ((row >> 1) & 3);
        bf16x8 Av = *(const bf16x8*)&Vs[cur][row * 32 + up * 8];
        O[mt][0] = MFMA32(Av, Bp[0][jc], O[mt][0]);
        O[mt][1] = MFMA32(Av, Bp[1][jc], O[mt][1]);
      }
    }
    __builtin_amdgcn_s_setprio(0);
    __syncthreads();   // single barrier: prefetch complete + all reads done
    cur ^= 1;
  }
#undef STAGE

  // epilogue: i on lanes -> direct coalesced stores
  float linv[2];
  linv[0] = 1.f / l_i[0];
  linv[1] = 1.f / l_i[1];
#pragma unroll
  for (int mt = 0; mt < 4; ++mt)
#pragma unroll
    for (int nt = 0; nt < 2; ++nt) {
      float* obase = out + ((size_t)(b * 1024 + h * 128 + mt * 32)) * 2048 +
                     it * 256 + wid * 64 + nt * 32 + l31;
#pragma unroll
      for (int rg = 0; rg < 16; ++rg) {
        int c = (rg & 3) + 8 * (rg >> 2) + 4 * q2;
        obase[(size_t)c * 2048] = O[mt][nt][rg] * linv[nt];
      }
    }
}

// ---------------------------------------------------------------------------
extern "C" void kernel_launch(void* const* d_in, const int* in_sizes, int n_in,
                              void* d_out, int out_size, void* d_ws, size_t ws_size,
                              hipStream_t stream) {
  const float* x   = (const float*)d_in[0];
  const float* wq  = (const float*)d_in[1];
  const float* bq  = (const float*)d_in[2];
  const float* gw1 = (const float*)d_in[3];
  const float* gb1 = (const float*)d_in[4];
  const float* wk  = (const float*)d_in[5];
  const float* bk  = (const float*)d_in[6];
  const float* gw2 = (const float*)d_in[7];
  const float* gb2 = (const float*)d_in[8];
  const float* wv  = (const float*)d_in[9];
  const float* bv  = (const float*)d_in[10];
  const float* gw3 = (const float*)d_in[11];
  const float* gb3 = (const float*)d_in[12];
  float* out = (float*)d_out;
  char* ws = (char*)d_ws;

  ushort_t* Qb = (ushort_t*)(ws);               // 33,554,432 B  [B,C,P] bf16
  ushort_t* Kb = (ushort_t*)(ws + 33554432);    // 33,554,432 B  [B,H,P,128] bf16
  ushort_t* Vb = (ushort_t*)(ws + 67108864);    // 33,554,432 B  [B,H,P,128] bf16
  float* stats = (float*)(ws + 100663296);      // 768 groups x {s1,s2}

  hipMemsetAsync(stats, 0, 1536 * sizeof(float), stream);
  conv_gn<<<dim3(16, 64, 3), 256, 0, stream>>>(x, wq, wk, wv, bq, bk, bv,
                                               Qb, Kb, Vb, stats);
  gn_apply<<<2048, 256, 0, stream>>>(Qb, stats, gw1, gb1, gw2, gb2, gw3, gb3);
  attn<<<dim3(8, 64), 256, 0, stream>>>(Qb, Kb, Vb, out);
}

// Round 8
// 372.166 us; speedup vs baseline: 1.2852x; 1.1306x over previous
//
#include <hip/hip_runtime.h>

typedef unsigned short ushort_t;
typedef float  f32x4   __attribute__((ext_vector_type(4)));
typedef float  f32x16  __attribute__((ext_vector_type(16)));
typedef __bf16 bf16x4  __attribute__((ext_vector_type(4)));
typedef __bf16 bf16x8  __attribute__((ext_vector_type(8)));
typedef unsigned uint2v __attribute__((ext_vector_type(2)));

#define MFMA16(a,b,c) __builtin_amdgcn_mfma_f32_16x16x32_bf16((a),(b),(c),0,0,0)
#define MFMA32(a,b,c) __builtin_amdgcn_mfma_f32_32x32x16_bf16((a),(b),(c),0,0,0)

__device__ __forceinline__ ushort_t f2bf(float f) {
  union { float f; unsigned u; } v; v.f = f;
  unsigned u = v.u;
  unsigned r = u + 0x7FFFu + ((u >> 16) & 1u);   // round-to-nearest-even
  return (ushort_t)(r >> 16);
}
__device__ __forceinline__ float bf2f(ushort_t s) {
  union { unsigned u; float f; } v; v.u = ((unsigned)s) << 16;
  return v.f;
}

// swap lanes 32-63 of a with lanes 0-31 of b (v_permlane32_swap_b32)
__device__ __forceinline__ void plswap(unsigned& a, unsigned& b) {
#if __has_builtin(__builtin_amdgcn_permlane32_swap)
  uint2v r = __builtin_amdgcn_permlane32_swap(a, b, false, false);
  a = r[0]; b = r[1];
#else
  asm("v_permlane32_swap_b32 %0, %1" : "+v"(a), "+v"(b));
#endif
}

// async global->LDS, 16B per lane. LDS dest is wave-uniform-base + lane*16;
// global src is per-lane (this is how the source-side swizzle is applied).
__device__ __forceinline__ void gload_lds16(const ushort_t* g, ushort_t* l) {
  __builtin_amdgcn_global_load_lds(
      (const __attribute__((address_space(1))) unsigned int*)g,
      (__attribute__((address_space(3))) unsigned int*)l, 16, 0, 0);
}

// ---------------------------------------------------------------------------
// Kernel 1: fused grouped conv (MFMA) + bias. R13:
// History: R4 branch-loop = best non-attn (235us); R6 direct-store = +32us
// (sector waste); R7 branch-split = +15us vs R4 (3x x-restage). R13 = R4
// branch-loop structure (x staged ONCE) + R7's proven LDS tricks:
//  * yl UNIONED into xl (xl dead after one-time Bx register reads).
//    LDS 47 -> 37KB => 4 blocks/CU; 1024 blocks = EXACTLY one round
//    (R4's 3/CU meant 2 ragged rounds).
//  * stats piggybacked on the existing yl barrier (R7-proven).
// grid (pc=16, g*b=64), 256 thr.
// Q branch -> [B][C][P]; K/V branches -> [B][H][P][128].
// ---------------------------------------------------------------------------
__global__ __launch_bounds__(256) void conv_gn(
    const float* __restrict__ x,
    const float* __restrict__ wq, const float* __restrict__ wk, const float* __restrict__ wv,
    const float* __restrict__ bq, const float* __restrict__ bk, const float* __restrict__ bv,
    ushort_t* __restrict__ Qb, ushort_t* __restrict__ Kb, ushort_t* __restrict__ Vb,
    float* __restrict__ stats) {
  int pc = blockIdx.x;
  int gz = blockIdx.y;
  int b = gz & 7, g = gz >> 3;
  int tid = threadIdx.x, lane = tid & 63, wid = tid >> 6;
  int l15 = lane & 15, q = lane >> 4;

  __shared__ __align__(16) ushort_t xl[128 * 72];   // [p][f]; reused as yl
  __shared__ __align__(16) ushort_t wl[128 * 72];   // [co][f], one branch
  __shared__ float biasl[128];
  __shared__ float redbuf[8];
  ushort_t* yl = xl;   // xl dead after Bx frag reads

  // stage x tile [64 f][128 p] f32 -> xl[p][f] bf16 (ONCE)
  const float* xsrc = x + ((size_t)(b * 512 + g * 64)) * 2048 + pc * 128;
#pragma unroll
  for (int r = 0; r < 8; ++r) {
    int chunk = tid + 256 * r;
    int c = chunk >> 5, p4 = chunk & 31;
    float4 v = *(const float4*)&xsrc[(size_t)c * 2048 + p4 * 4];
    xl[(p4 * 4 + 0) * 72 + c] = f2bf(v.x);
    xl[(p4 * 4 + 1) * 72 + c] = f2bf(v.y);
    xl[(p4 * 4 + 2) * 72 + c] = f2bf(v.z);
    xl[(p4 * 4 + 3) * 72 + c] = f2bf(v.w);
  }
  __syncthreads();

  // resident B-frags (wave's 32 p-cols); xl dead after this
  bf16x8 Bx[2][2];
#pragma unroll
  for (int n2 = 0; n2 < 2; ++n2)
#pragma unroll
    for (int kk = 0; kk < 2; ++kk)
      Bx[n2][kk] = *(const bf16x8*)&xl[((wid * 2 + n2) * 16 + l15) * 72 + kk * 32 + q * 8];

  for (int br = 0; br < 3; ++br) {
    const float* w    = (br == 0) ? wq : ((br == 1) ? wk : wv);
    const float* bias = (br == 0) ? bq : ((br == 1) ? bk : bv);
    ushort_t* dst     = (br == 0) ? Qb : ((br == 1) ? Kb : Vb);
    // wl overwrite safe: last Aw reads precede the trailing ngs barrier.
    const float* wsrc = w + (size_t)g * 128 * 64;
#pragma unroll
    for (int r = 0; r < 8; ++r) {
      int idx = (tid + 256 * r) << 2;
      float4 v = *(const float4*)&wsrc[idx];
      int row = idx >> 6, f = idx & 63;
      bf16x4 wv4 = {(__bf16)v.x, (__bf16)v.y, (__bf16)v.z, (__bf16)v.w};
      *(bf16x4*)&wl[row * 72 + f] = wv4;
    }
    if (tid < 128) biasl[tid] = bias[g * 128 + tid];
    __syncthreads();   // wl visible; also orders Bx reads before yl writes (br0)

    for (int ngs = 0; ngs < 4; ++ngs) {
      int co0 = ngs * 32;
      bf16x8 Aw[2][2];
#pragma unroll
      for (int m = 0; m < 2; ++m)
#pragma unroll
        for (int kk = 0; kk < 2; ++kk)
          Aw[m][kk] = *(const bf16x8*)&wl[(co0 + m * 16 + l15) * 72 + kk * 32 + q * 8];
      // acc[a][c2]: br==0 (swapped): a = n2 (p-tile), c2 = mw (co-tile);
      //             br>=1:           a = m  (co),     c2 = n2 (p)
      f32x4 acc[2][2];
#pragma unroll
      for (int a = 0; a < 2; ++a)
#pragma unroll
        for (int c2 = 0; c2 < 2; ++c2) acc[a][c2] = (f32x4){0.f, 0.f, 0.f, 0.f};
      if (br == 0) {
#pragma unroll
        for (int kk = 0; kk < 2; ++kk)
#pragma unroll
          for (int n2 = 0; n2 < 2; ++n2)
#pragma unroll
            for (int mw = 0; mw < 2; ++mw)
              acc[n2][mw] = MFMA16(Bx[n2][kk], Aw[mw][kk], acc[n2][mw]);
      } else {
#pragma unroll
        for (int kk = 0; kk < 2; ++kk)
#pragma unroll
          for (int n2 = 0; n2 < 2; ++n2)
#pragma unroll
            for (int m = 0; m < 2; ++m)
              acc[m][n2] = MFMA16(Aw[m][kk], Bx[n2][kk], acc[m][n2]);
      }

      float s1 = 0.f, s2 = 0.f;
      if (br == 0) {   // C: col=l15=co_local, row=4q+rg=p_local
#pragma unroll
        for (int n2 = 0; n2 < 2; ++n2)
#pragma unroll
          for (int mw = 0; mw < 2; ++mw) {
            float bi = biasl[co0 + mw * 16 + l15];
#pragma unroll
            for (int rg = 0; rg < 4; ++rg) {
              float y = acc[n2][mw][rg] + bi;
              acc[n2][mw][rg] = y;
              s1 += y; s2 += y * y;
            }
          }
      } else {         // C: col=l15=p_local, row=4q+rg=co_local
#pragma unroll
        for (int m = 0; m < 2; ++m)
#pragma unroll
          for (int n2 = 0; n2 < 2; ++n2)
#pragma unroll
            for (int rg = 0; rg < 4; ++rg) {
              float y = acc[m][n2][rg] + biasl[co0 + m * 16 + 4 * q + rg];
              acc[m][n2][rg] = y;
              s1 += y; s2 += y * y;
            }
      }
#pragma unroll
      for (int mask = 32; mask >= 1; mask >>= 1) {
        s1 += __shfl_xor(s1, mask, 64);
        s2 += __shfl_xor(s2, mask, 64);
      }
      if (lane == 0) { redbuf[wid * 2] = s1; redbuf[wid * 2 + 1] = s2; }

      // stage to yl (coalescing buffer; layouts match final memory order)
      if (br == 0) {   // yl: [32 c][136 p]
#pragma unroll
        for (int n2 = 0; n2 < 2; ++n2)
#pragma unroll
          for (int mw = 0; mw < 2; ++mw) {
            bf16x4 pk = {(__bf16)acc[n2][mw][0], (__bf16)acc[n2][mw][1],
                         (__bf16)acc[n2][mw][2], (__bf16)acc[n2][mw][3]};
            *(bf16x4*)&yl[(mw * 16 + l15) * 136 + (wid * 2 + n2) * 16 + 4 * q] = pk;
          }
      } else {         // yl: [128 p][40 c]
#pragma unroll
        for (int m = 0; m < 2; ++m)
#pragma unroll
          for (int n2 = 0; n2 < 2; ++n2) {
            bf16x4 pk = {(__bf16)acc[m][n2][0], (__bf16)acc[m][n2][1],
                         (__bf16)acc[m][n2][2], (__bf16)acc[m][n2][3]};
            *(bf16x4*)&yl[((wid * 2 + n2) * 16 + l15) * 40 + m * 16 + 4 * q] = pk;
          }
      }
      __syncthreads();   // yl + redbuf visible

      // fully-coalesced uint4 global stores (1KB/instr per wave)
      if (br == 0) {
#pragma unroll
        for (int r = 0; r < 2; ++r) {
          int chunk = tid + 256 * r;
          int row = chunk >> 4, ch = chunk & 15;
          *(uint4*)&dst[((size_t)(b * 1024 + g * 128 + co0 + row)) * 2048 + pc * 128 + ch * 8] =
              *(const uint4*)&yl[row * 136 + ch * 8];
        }
      } else {
#pragma unroll
        for (int r = 0; r < 2; ++r) {
          int chunk = tid + 256 * r;
          int row = chunk >> 2, ch = chunk & 3;
          *(uint4*)&dst[((size_t)(b * 8 + g) * 2048 + pc * 128 + row) * 128 + co0 + ch * 8] =
              *(const uint4*)&yl[row * 40 + ch * 8];
        }
      }
      if (tid == 0) {
        float S1 = redbuf[0] + redbuf[2] + redbuf[4] + redbuf[6];
        float S2 = redbuf[1] + redbuf[3] + redbuf[5] + redbuf[7];
        int sidx = (br * 8 + b) * 32 + g * 4 + ngs;
        atomicAdd(&stats[2 * sidx], S1);
        atomicAdd(&stats[2 * sidx + 1], S2);
      }
      __syncthreads();   // yl store-reads done -> yl/wl reusable
    }
  }
}

// ---------------------------------------------------------------------------
// Kernel 2: in-place GroupNorm affine + LeakyReLU over Qb and Vb ONLY
// (Kb's GN is fused into attn's Bq register load). grid-stride 2048x8.
// ---------------------------------------------------------------------------
__global__ __launch_bounds__(256) void gn_apply(
    ushort_t* __restrict__ buf, const float* __restrict__ stats,
    const float* __restrict__ gw1, const float* __restrict__ gb1,
    const float* __restrict__ gw3, const float* __restrict__ gb3) {
  const unsigned NQ = 16777216u;
  unsigned base = blockIdx.x * 256 + threadIdx.x;   // 524288 threads
  for (int itn = 0; itn < 8; ++itn) {
    unsigned gid = base + (unsigned)itn * 524288u;
    unsigned e2 = gid * 8;            // [0, 2*NQ)
    int br; unsigned local; size_t addr;
    if (e2 < NQ) { br = 0; local = e2;      addr = e2; }
    else         { br = 2; local = e2 - NQ; addr = (size_t)e2 + NQ; }  // skip Kb
    int b, c0;
    if (br == 0) { b = local >> 21; c0 = (local >> 11) & 1023; }
    else {
      int cih = local & 127; int h = (local >> 18) & 7;
      b = local >> 21; c0 = h * 128 + cih;
    }
    int ng = c0 >> 5;
    const float* gw = (br == 0) ? gw1 : gw3;
    const float* gb = (br == 0) ? gb1 : gb3;
    int sidx = (br * 8 + b) * 32 + ng;
    float mean = stats[2 * sidx] * (1.f / 65536.f);
    float var  = stats[2 * sidx + 1] * (1.f / 65536.f) - mean * mean;
    float rstd = rsqrtf(var + 1e-5f);
    uint4 d = *(uint4*)&buf[addr];
    ushort_t* pu = (ushort_t*)&d;
#pragma unroll
    for (int i = 0; i < 8; ++i) {
      int ci = (br == 0) ? c0 : (c0 + i);
      float a = rstd * gw[ci];
      float b2 = gb[ci] - mean * a;
      float yn = fmaf(bf2f(pu[i]), a, b2);
      yn = (yn >= 0.f) ? yn : 0.1f * yn;
      pu[i] = f2bf(yn);
    }
    *(uint4*)&buf[addr] = d;
  }
}

// ---------------------------------------------------------------------------
// Kernel 3: flash attention, 32x32x16 MFMA, S^T formulation. (R4/R6 172us
// core loop UNTOUCHED — register file at cap; j-unroll spills.)
// R13 addition: Kb (=fQ) GroupNorm+LeakyReLU fused into the ONE-TIME Bq
// register load (gn_apply no longer touches Kb): channel c = h*128 + d,
// d = dc*16 + q2*8 + e; 4 GN groups per thread, precomputed mean/rstd.
// ~800 VALU ops once per block = ~12/jt amortized.
//  * T12 register-P via cvt_pk + permlane32_swap.
//  * XCD remap: lin = bx + 8*by; it=(lin>>3)&7, bh=(lin&7)+8*(lin>>6).
//  * T5 setprio; defer-max; exp2 softmax; launch_bounds(256,2).
// LDS 32 KB, 2 blocks/CU.
// ---------------------------------------------------------------------------
__global__ __launch_bounds__(256, 2) void attn(
    const ushort_t* __restrict__ Qb, const ushort_t* __restrict__ Kb,
    const ushort_t* __restrict__ Vb, const float* __restrict__ stats,
    const float* __restrict__ gw2, const float* __restrict__ gb2,
    float* __restrict__ out) {
  __shared__ __align__(16) ushort_t fKs[2][32 * 128];   // [j][d] linear, 2x8192 B
  __shared__ __align__(16) ushort_t Vs[2][128 * 32];    // [c][j] linear, 2x8192 B

  int lin = blockIdx.x + 8 * blockIdx.y;           // XCD = lin % 8
  int it = (lin >> 3) & 7;
  int bh = (lin & 7) + 8 * (lin >> 6);             // XCD = bh & 7
  int b = bh >> 3, h = bh & 7;
  int tid = threadIdx.x, lane = tid & 63, wid = tid >> 6;
  int l31 = lane & 31, q2 = lane >> 5;
  // scale*log2(e): softmax in exp2 domain
  const float sl = 0.08838834764831845f * 1.4426950408889634f;

  // resident fQ B-frags: B[k=d][n=i], n-col = l31 -> row i (one-time load)
  bf16x8 Bq[2][8];
#pragma unroll
  for (int nt = 0; nt < 2; ++nt) {
    const ushort_t* fQp =
        Kb + ((size_t)bh * 2048 + it * 256 + wid * 64 + nt * 32 + l31) * 128 + q2 * 8;
#pragma unroll
    for (int dc = 0; dc < 8; ++dc) Bq[nt][dc] = *(const bf16x8*)&fQp[dc * 16];
  }
  // fused GN + LeakyReLU on Bq (K-branch stats: br=1)
  {
    float mean4[4], rstd4[4];
#pragma unroll
    for (int gi = 0; gi < 4; ++gi) {
      int sidx = (1 * 8 + b) * 32 + h * 4 + gi;
      float mean = stats[2 * sidx] * (1.f / 65536.f);
      float var  = stats[2 * sidx + 1] * (1.f / 65536.f) - mean * mean;
      mean4[gi] = mean;
      rstd4[gi] = rsqrtf(var + 1e-5f);
    }
#pragma unroll
    for (int dc = 0; dc < 8; ++dc) {
      int d0 = dc * 16 + q2 * 8;
      int gi = d0 >> 5;
#pragma unroll
      for (int e = 0; e < 8; ++e) {
        int c0 = h * 128 + d0 + e;
        float a  = rstd4[gi] * gw2[c0];
        float b2 = gb2[c0] - mean4[gi] * a;
        float v0 = fmaf((float)Bq[0][dc][e], a, b2);
        float v1 = fmaf((float)Bq[1][dc][e], a, b2);
        v0 = fmaxf(v0, 0.1f * v0);   // LeakyReLU(0.1)
        v1 = fmaxf(v1, 0.1f * v1);
        Bq[0][dc][e] = (__bf16)v0;
        Bq[1][dc][e] = (__bf16)v1;
      }
    }
  }

  float m2[2], l_i[2];
  m2[0] = m2[1] = -3e38f;
  l_i[0] = l_i[1] = 0.f;
  f32x16 O[4][2];
#pragma unroll
  for (int mt = 0; mt < 4; ++mt)
#pragma unroll
    for (int nt = 0; nt < 2; ++nt) O[mt][nt] = (f32x16)(0.f);

  const ushort_t* fKg = Vb + (size_t)bh * 2048 * 128;
  const ushort_t* fVg = Qb + ((size_t)(b * 1024 + h * 128)) * 2048;

  // ---- staging: 512 16B-units per tensor-tile; each thread issues 2+2.
  // LDS is linear in unit index n (wave-uniform base + lane*16); the XOR
  // swizzle is applied to the unit index on the GLOBAL side.
#define STAGE(JT, NB)                                                          \
  do {                                                                         \
    _Pragma("unroll")                                                          \
    for (int r = 0; r < 2; ++r) {                                              \
      int n = tid + 256 * r;                                                   \
      int kr = n >> 4, ku = (n & 15) ^ (kr & 7);                               \
      gload_lds16(fKg + (size_t)(JT) * 4096 + kr * 128 + ku * 8,               \
                  &fKs[NB][n * 8]);                                            \
      int vr = n >> 2, vu = (n & 3) ^ ((vr >> 1) & 3);                         \
      gload_lds16(fVg + (size_t)vr * 2048 + (JT) * 32 + vu * 8,                \
                  &Vs[NB][n * 8]);                                             \
    }                                                                          \
  } while (0)

  STAGE(0, 0);
  __syncthreads();   // vmcnt(0) drain + barrier: tile 0 visible
  int cur = 0;

  for (int jt = 0; jt < 64; ++jt) {
    if (jt < 63) STAGE(jt + 1, cur ^ 1);   // async prefetch into idle buffer

    // S^T = fK . fQ^T : 8 swizzled A-reads, 16 MFMAs
    f32x16 ST[2];
    ST[0] = (f32x16)(0.f);
    ST[1] = (f32x16)(0.f);
    __builtin_amdgcn_s_setprio(1);
#pragma unroll
    for (int dc = 0; dc < 8; ++dc) {
      int up = (dc * 2 + q2) ^ (l31 & 7);
      bf16x8 Ak = *(const bf16x8*)&fKs[cur][l31 * 128 + up * 8];
      ST[0] = MFMA32(Ak, Bq[0][dc], ST[0]);
      ST[1] = MFMA32(Ak, Bq[1][dc], ST[1]);
    }
    __builtin_amdgcn_s_setprio(0);

    // online softmax over j; lane covers i (j split across q2).
    // P -> bf16 MFMA B-frags IN REGISTER via cvt_pk + permlane32_swap.
    bf16x8 Bp[2][2];   // [nt][jc]
#pragma unroll
    for (int nt = 0; nt < 2; ++nt) {
      float vmax = ST[nt][0];
#pragma unroll
      for (int rg = 1; rg < 16; ++rg) vmax = fmaxf(vmax, ST[nt][rg]);
      float v2 = vmax * sl;
      v2 = fmaxf(v2, __shfl_xor(v2, 32, 64));
      float al = 1.f;
      bool need = !__all(v2 <= m2[nt] + 8.f);   // defer-max: wave-uniform
      if (need) {
        float mn2 = fmaxf(m2[nt], v2);
        al = __builtin_amdgcn_exp2f(m2[nt] - mn2);
        m2[nt] = mn2;
      }
      float mn = m2[nt];
      float p16[16];
      float rs = 0.f;
#pragma unroll
      for (int rg = 0; rg < 16; ++rg) {
        p16[rg] = __builtin_amdgcn_exp2f(fmaf(ST[nt][rg], sl, -mn));
        rs += p16[rg];
      }
      rs += __shfl_xor(rs, 32, 64);
      l_i[nt] = l_i[nt] * al + rs;
      if (need) {   // O rescale only when running max moved (i on lanes)
#pragma unroll
        for (int mt = 0; mt < 4; ++mt)
#pragma unroll
          for (int rg = 0; rg < 16; ++rg) O[mt][nt][rg] *= al;
      }
#pragma unroll
      for (int jc = 0; jc < 2; ++jc) {
        unsigned pa, pb, pc_, pd;
        asm("v_cvt_pk_bf16_f32 %0, %1, %2"
            : "=v"(pa) : "v"(p16[jc * 8 + 0]), "v"(p16[jc * 8 + 1]));
        asm("v_cvt_pk_bf16_f32 %0, %1, %2"
            : "=v"(pc_) : "v"(p16[jc * 8 + 2]), "v"(p16[jc * 8 + 3]));
        asm("v_cvt_pk_bf16_f32 %0, %1, %2"
            : "=v"(pb) : "v"(p16[jc * 8 + 4]), "v"(p16[jc * 8 + 5]));
        asm("v_cvt_pk_bf16_f32 %0, %1, %2"
            : "=v"(pd) : "v"(p16[jc * 8 + 6]), "v"(p16[jc * 8 + 7]));
        plswap(pa, pb);
        plswap(pc_, pd);
        union { unsigned u[4]; bf16x8 v; } fr;
        fr.u[0] = pa; fr.u[1] = pc_; fr.u[2] = pb; fr.u[3] = pd;
        Bp[nt][jc] = fr.v;
      }
    }

    // O^T += V . P^T : 8 swizzled V-reads, 16 MFMAs (P in registers)
    __builtin_amdgcn_s_setprio(1);
#pragma unroll
    for (int jc = 0; jc < 2; ++jc) {
#pragma unroll
      for (int mt = 0; mt < 4; ++mt) {
        int row = mt * 32 + l31;
        int up = (jc * 2 + q2) ^ ((row >> 1) & 3);
        bf16x8 Av = *(const bf16x8*)&Vs[cur][row * 32 + up * 8];
        O[mt][0] = MFMA32(Av, Bp[0][jc], O[mt][0]);
        O[mt][1] = MFMA32(Av, Bp[1][jc], O[mt][1]);
      }
    }
    __builtin_amdgcn_s_setprio(0);
    __syncthreads();   // single barrier: prefetch complete + all reads done
    cur ^= 1;
  }
#undef STAGE

  // epilogue: i on lanes -> direct coalesced stores
  float linv[2];
  linv[0] = 1.f / l_i[0];
  linv[1] = 1.f / l_i[1];
#pragma unroll
  for (int mt = 0; mt < 4; ++mt)
#pragma unroll
    for (int nt = 0; nt < 2; ++nt) {
      float* obase = out + ((size_t)(b * 1024 + h * 128 + mt * 32)) * 2048 +
                     it * 256 + wid * 64 + nt * 32 + l31;
#pragma unroll
      for (int rg = 0; rg < 16; ++rg) {
        int c = (rg & 3) + 8 * (rg >> 2) + 4 * q2;
        obase[(size_t)c * 2048] = O[mt][nt][rg] * linv[nt];
      }
    }
}

// ---------------------------------------------------------------------------
extern "C" void kernel_launch(void* const* d_in, const int* in_sizes, int n_in,
                              void* d_out, int out_size, void* d_ws, size_t ws_size,
                              hipStream_t stream) {
  const float* x   = (const float*)d_in[0];
  const float* wq  = (const float*)d_in[1];
  const float* bq  = (const float*)d_in[2];
  const float* gw1 = (const float*)d_in[3];
  const float* gb1 = (const float*)d_in[4];
  const float* wk  = (const float*)d_in[5];
  const float* bk  = (const float*)d_in[6];
  const float* gw2 = (const float*)d_in[7];
  const float* gb2 = (const float*)d_in[8];
  const float* wv  = (const float*)d_in[9];
  const float* bv  = (const float*)d_in[10];
  const float* gw3 = (const float*)d_in[11];
  const float* gb3 = (const float*)d_in[12];
  float* out = (float*)d_out;
  char* ws = (char*)d_ws;

  ushort_t* Qb = (ushort_t*)(ws);               // 33,554,432 B  [B,C,P] bf16
  ushort_t* Kb = (ushort_t*)(ws + 33554432);    // 33,554,432 B  [B,H,P,128] bf16
  ushort_t* Vb = (ushort_t*)(ws + 67108864);    // 33,554,432 B  [B,H,P,128] bf16
  float* stats = (float*)(ws + 100663296);      // 768 groups x {s1,s2}

  hipMemsetAsync(stats, 0, 1536 * sizeof(float), stream);
  conv_gn<<<dim3(16, 64), 256, 0, stream>>>(x, wq, wk, wv, bq, bk, bv,
                                            Qb, Kb, Vb, stats);
  gn_apply<<<2048, 256, 0, stream>>>(Qb, stats, gw1, gb1, gw3, gb3);
  attn<<<dim3(8, 64), 256, 0, stream>>>(Qb, Kb, Vb, stats, gw2, gb2, out);
}